// Round 1
// 7338.285 us; speedup vs baseline: 1.4734x; 1.4734x over previous
//
#include <hip/hip_runtime.h>
#include <hip/hip_bf16.h>
#include <math.h>

#define B_ 4
#define L_ 301
#define D_ 768
#define DI_ 1536
#define NP_ 300
#define POS_ 150
#define M_ 1204
#define SCHUNK 64

typedef __bf16 bf16;
typedef __attribute__((ext_vector_type(8))) __bf16 bf16x8;
typedef __attribute__((ext_vector_type(4))) float floatx4;

__device__ __forceinline__ float siluf(float x) { return x / (1.f + __expf(-x)); }
__device__ __forceinline__ float softplusf(float x) { return x > 20.f ? x : log1pf(__expf(x)); }

// ---------------------------------------------------------------------------
// MFMA bf16 GEMM, z-batched (blockIdx.z selects operand set 0/1):
// C[M,Nw] = act(A[M,K]bf16 @ W[Nw,K]f32^T + bias)
// 128x128 tile, BK=32, 256 thr (4 waves 2x2), 4x4 16x16x32 frags/wave.
// Used for in_proj (grid 240) and dt (grid 480) which already have enough
// blocks; latency-bound small-grid GEMMs moved to the split-K variants below.
// ---------------------------------------------------------------------------
__global__ __launch_bounds__(256) void gemm_mfma(
    const bf16* __restrict__ A0, const bf16* __restrict__ A1, int lda,
    const float* __restrict__ W0, const float* __restrict__ W1, int ldw,
    const float* __restrict__ bias0, const float* __restrict__ bias1,
    float* __restrict__ C0, float* __restrict__ C1,
    bf16* __restrict__ Cb0, bf16* __restrict__ Cb1, int ldc,
    int M, int Nw, int Kw, int Ksteps, int act)
{
    const int zz = blockIdx.z;
    const bf16* A = zz ? A1 : A0;
    const float* W = zz ? W1 : W0;
    const float* bias = zz ? bias1 : bias0;
    float* C = zz ? C1 : C0;
    bf16* Cb = zz ? Cb1 : Cb0;

    __shared__ bf16 As[128 * 32];
    __shared__ bf16 Ws[128 * 32];
    const int t = threadIdx.x;
    const int bm = blockIdx.y * 128;
    const int bn = blockIdx.x * 128;
    const int lane = t & 63;
    const int wid = t >> 6;
    const int wr = wid >> 1, wc = wid & 1;
    const int ar = t >> 2;
    const int ac = (t & 3) * 8;

    const bool fullNK = ((Nw & 127) == 0) && ((Kw & 31) == 0);

    floatx4 acc[4][4] = {};

    for (int ks = 0; ks < Ksteps; ks++) {
        const int k0 = ks * 32;
#pragma unroll
        for (int c2 = 0; c2 < 2; c2++) {
            int r = ar + c2 * 64;
            int gm = bm + r; if (gm >= M) gm = M - 1;
            const bf16* gp = A + (size_t)gm * lda + k0 + ac;
            __builtin_amdgcn_global_load_lds(
                (const __attribute__((address_space(1))) void*)gp,
                (__attribute__((address_space(3))) void*)(As + r * 32 + ac),
                16, 0, 0);
        }
#pragma unroll
        for (int c2 = 0; c2 < 2; c2++) {
            int r = ar + c2 * 64;
            int gn = bn + r;
            float vv[8];
            if (fullNK) {
                const floatx4* wp4 = (const floatx4*)(W + (size_t)gn * ldw + k0 + ac);
                floatx4 a4 = wp4[0], b4 = wp4[1];
#pragma unroll
                for (int e = 0; e < 4; e++) { vv[e] = a4[e]; vv[e + 4] = b4[e]; }
            } else {
                const float* wp = W + (size_t)gn * ldw + k0 + ac;
#pragma unroll
                for (int e = 0; e < 8; e++) {
                    int kk = k0 + ac + e;
                    vv[e] = (gn < Nw && kk < Kw) ? wp[e] : 0.f;
                }
            }
            bf16x8 pk;
#pragma unroll
            for (int e = 0; e < 8; e++) pk[e] = (bf16)vv[e];
            *(bf16x8*)(Ws + r * 32 + ac) = pk;
        }
        __syncthreads();
        const int ra = wr * 64 + (lane & 15);
        const int rb = wc * 64 + (lane & 15);
        const int kb = (lane >> 4) * 8;
        bf16x8 af[4], bfm[4];
#pragma unroll
        for (int i = 0; i < 4; i++)
            af[i] = *(const bf16x8*)(As + (ra + i * 16) * 32 + kb);
#pragma unroll
        for (int j = 0; j < 4; j++)
            bfm[j] = *(const bf16x8*)(Ws + (rb + j * 16) * 32 + kb);
#pragma unroll
        for (int i = 0; i < 4; i++)
#pragma unroll
            for (int j = 0; j < 4; j++)
                acc[i][j] = __builtin_amdgcn_mfma_f32_16x16x32_bf16(af[i], bfm[j], acc[i][j], 0, 0, 0);
        __syncthreads();
    }
#pragma unroll
    for (int i = 0; i < 4; i++) {
#pragma unroll
        for (int j = 0; j < 4; j++) {
            int n = bn + wc * 64 + j * 16 + (lane & 15);
            if (n >= Nw) continue;
            float bv = (act >= 1) ? bias[n] : 0.f;
#pragma unroll
            for (int r = 0; r < 4; r++) {
                int m = bm + wr * 64 + i * 16 + (lane >> 4) * 4 + r;
                if (m >= M) continue;
                float v = acc[i][j][r] + bv;
                if (act == 2) v = softplusf(v);
                C[(size_t)m * ldc + n] = v;
                if (Cb) Cb[(size_t)m * ldc + n] = (bf16)v;
            }
        }
    }
}

// ---------------------------------------------------------------------------
// Split-K MFMA GEMM (2-dir): blockIdx.z = dir*SK + chunk. Writes f32 partial
// C-tiles to Cp[z]; a reduce kernel sums them. Kw assumed %32==0; W rows
// guarded (vectorized when in-range) so Nw<128 (xproj N=80) stays fast.
// Grid-starved GEMMs (xproj: 20 blocks) become (20*SK) blocks.
// ---------------------------------------------------------------------------
__global__ __launch_bounds__(256) void gemm_mfma_sk(
    const bf16* __restrict__ A0, const bf16* __restrict__ A1, int lda,
    const float* __restrict__ W0, const float* __restrict__ W1, int ldw,
    float* __restrict__ Cp, size_t chunkStride, int ldc,
    int M, int Nw, int KstepsPer, int SK)
{
    const int z = blockIdx.z;
    const int dir = z / SK;
    const int chunk = z % SK;
    const bf16* A = dir ? A1 : A0;
    const float* W = dir ? W1 : W0;
    float* C = Cp + (size_t)z * chunkStride;

    __shared__ bf16 As[128 * 32];
    __shared__ bf16 Ws[128 * 32];
    const int t = threadIdx.x;
    const int bm = blockIdx.y * 128;
    const int bn = blockIdx.x * 128;
    const int lane = t & 63;
    const int wid = t >> 6;
    const int wr = wid >> 1, wc = wid & 1;
    const int ar = t >> 2;
    const int ac = (t & 3) * 8;

    floatx4 acc[4][4] = {};

    for (int ks = 0; ks < KstepsPer; ks++) {
        const int k0 = (chunk * KstepsPer + ks) * 32;
#pragma unroll
        for (int c2 = 0; c2 < 2; c2++) {
            int r = ar + c2 * 64;
            int gm = bm + r; if (gm >= M) gm = M - 1;
            const bf16* gp = A + (size_t)gm * lda + k0 + ac;
            __builtin_amdgcn_global_load_lds(
                (const __attribute__((address_space(1))) void*)gp,
                (__attribute__((address_space(3))) void*)(As + r * 32 + ac),
                16, 0, 0);
        }
#pragma unroll
        for (int c2 = 0; c2 < 2; c2++) {
            int r = ar + c2 * 64;
            int gn = bn + r;
            bf16x8 pk;
            if (gn < Nw) {
                const floatx4* wp4 = (const floatx4*)(W + (size_t)gn * ldw + k0 + ac);
                floatx4 a4 = wp4[0], b4 = wp4[1];
#pragma unroll
                for (int e = 0; e < 4; e++) { pk[e] = (bf16)a4[e]; pk[e + 4] = (bf16)b4[e]; }
            } else {
#pragma unroll
                for (int e = 0; e < 8; e++) pk[e] = (bf16)0.f;
            }
            *(bf16x8*)(Ws + r * 32 + ac) = pk;
        }
        __syncthreads();
        const int ra = wr * 64 + (lane & 15);
        const int rb = wc * 64 + (lane & 15);
        const int kb = (lane >> 4) * 8;
        bf16x8 af[4], bfm[4];
#pragma unroll
        for (int i = 0; i < 4; i++)
            af[i] = *(const bf16x8*)(As + (ra + i * 16) * 32 + kb);
#pragma unroll
        for (int j = 0; j < 4; j++)
            bfm[j] = *(const bf16x8*)(Ws + (rb + j * 16) * 32 + kb);
#pragma unroll
        for (int i = 0; i < 4; i++)
#pragma unroll
            for (int j = 0; j < 4; j++)
                acc[i][j] = __builtin_amdgcn_mfma_f32_16x16x32_bf16(af[i], bfm[j], acc[i][j], 0, 0, 0);
        __syncthreads();
    }
#pragma unroll
    for (int i = 0; i < 4; i++) {
#pragma unroll
        for (int j = 0; j < 4; j++) {
            int n = bn + wc * 64 + j * 16 + (lane & 15);
            if (n >= Nw) continue;
#pragma unroll
            for (int r = 0; r < 4; r++) {
                int m = bm + wr * 64 + i * 16 + (lane >> 4) * 4 + r;
                if (m >= M) continue;
                C[(size_t)m * ldc + n] = acc[i][j][r];
            }
        }
    }
}

// ---------------------------------------------------------------------------
// out_proj split-K GEMM: A = bf16(0.5*(Af+Ab)) merged during staging.
// blockIdx.z = K-chunk. fullNK assumed. Partials to Cp.
// ---------------------------------------------------------------------------
__global__ __launch_bounds__(256) void gemm_mfma_avg_sk(
    const bf16* __restrict__ Af, const bf16* __restrict__ Ab, int lda,
    const float* __restrict__ W, int ldw,
    float* __restrict__ Cp, size_t chunkStride, int ldc,
    int M, int Nw, int KstepsPer, int SK)
{
    const int chunk = blockIdx.z;
    float* C = Cp + (size_t)chunk * chunkStride;

    __shared__ bf16 As[128 * 32];
    __shared__ bf16 Ws[128 * 32];
    const int t = threadIdx.x;
    const int bm = blockIdx.y * 128;
    const int bn = blockIdx.x * 128;
    const int lane = t & 63;
    const int wid = t >> 6;
    const int wr = wid >> 1, wc = wid & 1;
    const int ar = t >> 2;
    const int ac = (t & 3) * 8;

    floatx4 acc[4][4] = {};

    for (int ks = 0; ks < KstepsPer; ks++) {
        const int k0 = (chunk * KstepsPer + ks) * 32;
#pragma unroll
        for (int c2 = 0; c2 < 2; c2++) {
            int r = ar + c2 * 64;
            int gm = bm + r; if (gm >= M) gm = M - 1;
            bf16x8 a8 = *(const bf16x8*)(Af + (size_t)gm * lda + k0 + ac);
            bf16x8 b8 = *(const bf16x8*)(Ab + (size_t)gm * lda + k0 + ac);
            bf16x8 pk;
#pragma unroll
            for (int e = 0; e < 8; e++)
                pk[e] = (bf16)(0.5f * ((float)a8[e] + (float)b8[e]));
            *(bf16x8*)(As + r * 32 + ac) = pk;
        }
#pragma unroll
        for (int c2 = 0; c2 < 2; c2++) {
            int r = ar + c2 * 64;
            int gn = bn + r;
            const floatx4* wp4 = (const floatx4*)(W + (size_t)gn * ldw + k0 + ac);
            floatx4 a4 = wp4[0], b4 = wp4[1];
            bf16x8 pk;
#pragma unroll
            for (int e = 0; e < 4; e++) { pk[e] = (bf16)a4[e]; pk[e + 4] = (bf16)b4[e]; }
            *(bf16x8*)(Ws + r * 32 + ac) = pk;
        }
        __syncthreads();
        const int ra = wr * 64 + (lane & 15);
        const int rb = wc * 64 + (lane & 15);
        const int kb = (lane >> 4) * 8;
        bf16x8 af[4], bfm[4];
#pragma unroll
        for (int i = 0; i < 4; i++)
            af[i] = *(const bf16x8*)(As + (ra + i * 16) * 32 + kb);
#pragma unroll
        for (int j = 0; j < 4; j++)
            bfm[j] = *(const bf16x8*)(Ws + (rb + j * 16) * 32 + kb);
#pragma unroll
        for (int i = 0; i < 4; i++)
#pragma unroll
            for (int j = 0; j < 4; j++)
                acc[i][j] = __builtin_amdgcn_mfma_f32_16x16x32_bf16(af[i], bfm[j], acc[i][j], 0, 0, 0);
        __syncthreads();
    }
#pragma unroll
    for (int i = 0; i < 4; i++) {
#pragma unroll
        for (int j = 0; j < 4; j++) {
            int n = bn + wc * 64 + j * 16 + (lane & 15);
            if (n >= Nw) continue;
#pragma unroll
            for (int r = 0; r < 4; r++) {
                int m = bm + wr * 64 + i * 16 + (lane >> 4) * 4 + r;
                if (m >= M) continue;
                C[(size_t)m * ldc + n] = acc[i][j][r];
            }
        }
    }
}

// ---------------------------------------------------------------------------
// Split-K reduce: C = act(sum_chunks Cp + bias); optional bf16 mirror.
// blockIdx.y = dir (partials for dir d start at Cp + d*SK*chunkStride).
// ---------------------------------------------------------------------------
__global__ void reduce_sk2(const float* __restrict__ Cp, size_t chunkStride, int SK,
                           const float* __restrict__ bias0,
                           float* __restrict__ C0, float* __restrict__ C1,
                           bf16* __restrict__ Cb0, bf16* __restrict__ Cb1,
                           int total, int ldn, int act)
{
    const int dir = blockIdx.y;
    const float* P = Cp + (size_t)dir * SK * chunkStride;
    float* C = dir ? C1 : C0;
    bf16* Cb = dir ? Cb1 : Cb0;
    int idx = blockIdx.x * 256 + threadIdx.x;
    if (idx >= total) return;
    float s = 0.f;
    for (int c = 0; c < SK; c++) s += P[(size_t)c * chunkStride + idx];
    if (act >= 1) s += bias0[idx % ldn];
    if (act == 2) s = softplusf(s);
    C[idx] = s;
    if (Cb) Cb[idx] = (bf16)s;
}

// ---------------------------------------------------------------------------
// Patch-embed MFMA GEMM, split-K over blockIdx.z (SK=8, 48 ksteps/chunk).
// Was 60 blocks / 2.85% occupancy / 486us -> now 480 blocks, partials + reduce.
// ---------------------------------------------------------------------------
__global__ __launch_bounds__(256) void gemm_patch_mfma(
    const float* __restrict__ img, const float* __restrict__ W,
    float* __restrict__ Cp)
{
    __shared__ bf16 As[128 * 32];
    __shared__ bf16 Ws[128 * 32];
    const int t = threadIdx.x;
    const int bm = blockIdx.y * 128;
    const int bn = blockIdx.x * 128;
    const int chunk = blockIdx.z;
    const int lane = t & 63;
    const int wid = t >> 6;
    const int wr = wid >> 1, wc = wid & 1;
    const int ar = t >> 2;
    const int ac = (t & 3) * 8;
    const int M = 1200, ldw = 12288, ldc = 768;
    float* C = Cp + (size_t)chunk * M * ldc;

    const float* abase[2];
#pragma unroll
    for (int c2 = 0; c2 < 2; c2++) {
        int gm = bm + ar + c2 * 64; if (gm >= M) gm = M - 1;
        int b = gm / 300, rem = gm % 300;
        int gi = rem / 15, gj = rem % 15;
        abase[c2] = img + ((size_t)(b * 3) * 1280 + gi * 64) * 960 + gj * 64;
    }

    floatx4 acc[4][4] = {};

    for (int ks = 0; ks < 48; ks++) {
        const int k0 = (chunk * 48 + ks) * 32;
        const int k = k0 + ac;
        const int q = k & 63, p = (k >> 6) & 63, c = k >> 12;
#pragma unroll
        for (int c2 = 0; c2 < 2; c2++) {
            int r = ar + c2 * 64;
            const float* ip = abase[c2] + ((size_t)c * 1280 + p) * 960 + q;
            const floatx4* ip4 = (const floatx4*)ip;
            floatx4 a4 = ip4[0], b4 = ip4[1];
            bf16x8 pk;
#pragma unroll
            for (int e = 0; e < 4; e++) { pk[e] = (bf16)a4[e]; pk[e + 4] = (bf16)b4[e]; }
            *(bf16x8*)(As + r * 32 + ac) = pk;
        }
#pragma unroll
        for (int c2 = 0; c2 < 2; c2++) {
            int r = ar + c2 * 64;
            int gn = bn + r;
            const floatx4* wp4 = (const floatx4*)(W + (size_t)gn * ldw + k);
            floatx4 a4 = wp4[0], b4 = wp4[1];
            bf16x8 pk;
#pragma unroll
            for (int e = 0; e < 4; e++) { pk[e] = (bf16)a4[e]; pk[e + 4] = (bf16)b4[e]; }
            *(bf16x8*)(Ws + r * 32 + ac) = pk;
        }
        __syncthreads();
        const int ra = wr * 64 + (lane & 15);
        const int rb = wc * 64 + (lane & 15);
        const int kb = (lane >> 4) * 8;
        bf16x8 af[4], bfm[4];
#pragma unroll
        for (int i = 0; i < 4; i++)
            af[i] = *(const bf16x8*)(As + (ra + i * 16) * 32 + kb);
#pragma unroll
        for (int j = 0; j < 4; j++)
            bfm[j] = *(const bf16x8*)(Ws + (rb + j * 16) * 32 + kb);
#pragma unroll
        for (int i = 0; i < 4; i++)
#pragma unroll
            for (int j = 0; j < 4; j++)
                acc[i][j] = __builtin_amdgcn_mfma_f32_16x16x32_bf16(af[i], bfm[j], acc[i][j], 0, 0, 0);
        __syncthreads();
    }
#pragma unroll
    for (int i = 0; i < 4; i++) {
#pragma unroll
        for (int j = 0; j < 4; j++) {
            int n = bn + wc * 64 + j * 16 + (lane & 15);
#pragma unroll
            for (int r = 0; r < 4; r++) {
                int m = bm + wr * 64 + i * 16 + (lane >> 4) * 4 + r;
                if (m >= M) continue;
                C[(size_t)m * ldc + n] = acc[i][j][r];
            }
        }
    }
}

// ---------------------------------------------------------------------------
// fp32 GEMM for the tiny head matmul.
// ---------------------------------------------------------------------------
__global__ void gemm_bt(const float* __restrict__ A, int lda,
                        const float* __restrict__ W, int ldw,
                        const float* __restrict__ bias,
                        float* __restrict__ C, int ldc,
                        int M, int N, int K, int act) {
    __shared__ float As[16][68];
    __shared__ float Ws[16][68];
    const int tid = threadIdx.x;
    const int bm = blockIdx.y * 64;
    const int bn = blockIdx.x * 64;
    const int tx = tid & 15, ty = tid >> 4;
    float acc[4][4] = {};
    const int lk = tid & 15;
    const int lm = tid >> 4;
    for (int k0 = 0; k0 < K; k0 += 16) {
        const int ak = k0 + lk;
#pragma unroll
        for (int i = 0; i < 4; i++) {
            int m = bm + lm + i * 16;
            float v = 0.f;
            if (m < M && ak < K) v = A[(long)m * lda + ak];
            As[lk][lm + i * 16] = v;
        }
#pragma unroll
        for (int i = 0; i < 4; i++) {
            int n = bn + lm + i * 16;
            float v = 0.f;
            if (n < N && ak < K) v = W[(long)n * ldw + ak];
            Ws[lk][lm + i * 16] = v;
        }
        __syncthreads();
#pragma unroll
        for (int kk = 0; kk < 16; kk++) {
            float a[4], w[4];
#pragma unroll
            for (int i = 0; i < 4; i++) a[i] = As[kk][ty * 4 + i];
#pragma unroll
            for (int j = 0; j < 4; j++) w[j] = Ws[kk][tx * 4 + j];
#pragma unroll
            for (int i = 0; i < 4; i++)
#pragma unroll
                for (int j = 0; j < 4; j++) acc[i][j] += a[i] * w[j];
        }
        __syncthreads();
    }
#pragma unroll
    for (int i = 0; i < 4; i++) {
        int m = bm + ty * 4 + i;
        if (m >= M) continue;
#pragma unroll
        for (int j = 0; j < 4; j++) {
            int n = bn + tx * 4 + j;
            if (n >= N) continue;
            float v = acc[i][j];
            if (act >= 1) v += bias[n];
            C[(long)m * ldc + n] = v;
        }
    }
}

// ---------------------------------------------------------------------------
__global__ void assemble(const float* __restrict__ xt, const float* __restrict__ cls,
                         const float* __restrict__ pos, float* __restrict__ x,
                         float* __restrict__ res) {
    int idx = blockIdx.x * 256 + threadIdx.x;
    if (idx >= B_ * L_ * D_) return;
    int d = idx % D_;
    int l = (idx / D_) % L_;
    int b = idx / (D_ * L_);
    float v;
    if (l == POS_) {
        v = cls[d];
    } else {
        int p = (l < POS_) ? l : l - 1;
        v = xt[((long)b * NP_ + p) * D_ + d];
    }
    x[idx] = v + pos[l * D_ + d];
    res[idx] = 0.f;
}

// res += h ; hn = bf16(rms(res) * w)
__global__ void add_rms(float* __restrict__ res, const float* __restrict__ h,
                        const float* __restrict__ w, bf16* __restrict__ hn) {
    int row = blockIdx.x;
    float* rr = res + (long)row * D_;
    const float* hr = h + (long)row * D_;
    float v[3];
    float ss = 0.f;
#pragma unroll
    for (int i = 0; i < 3; i++) {
        int d = threadIdx.x + i * 256;
        float t = rr[d] + hr[d];
        v[i] = t;
        ss += t * t;
    }
#pragma unroll
    for (int off = 1; off < 64; off <<= 1) ss += __shfl_xor(ss, off);
    __shared__ float red[4];
    __shared__ float inv;
    if ((threadIdx.x & 63) == 0) red[threadIdx.x >> 6] = ss;
    __syncthreads();
    if (threadIdx.x == 0) {
        float s = red[0] + red[1] + red[2] + red[3];
        inv = rsqrtf(s / (float)D_ + 1e-5f);
    }
    __syncthreads();
    float iv = inv;
#pragma unroll
    for (int i = 0; i < 3; i++) {
        int d = threadIdx.x + i * 256;
        rr[d] = v[i];
        hn[(long)row * D_ + d] = (bf16)(v[i] * iv * w[d]);
    }
}

// Depthwise causal conv (K=4) + silu, both directions in one dispatch.
__global__ void conv_silu2(const float* __restrict__ xz,
                           const float* __restrict__ wf, const float* __restrict__ bf_,
                           const float* __restrict__ wb, const float* __restrict__ bb_,
                           float* __restrict__ of, bf16* __restrict__ ofb,
                           float* __restrict__ ob, bf16* __restrict__ obb) {
    int idx = blockIdx.x * 256 + threadIdx.x;
    if (idx >= B_ * L_ * DI_) return;
    const int rev = blockIdx.y;
    const float* w = rev ? wb : wf;
    const float* bias = rev ? bb_ : bf_;
    float* out = rev ? ob : of;
    bf16* outb = rev ? obb : ofb;
    int d = idx % DI_;
    int l = (idx / DI_) % L_;
    int b = idx / (DI_ * L_);
    float acc = bias[d];
#pragma unroll
    for (int k = 0; k < 4; k++) {
        int ls = l - 3 + k;
        if (ls < 0) continue;
        int lsrc = rev ? (L_ - 1 - ls) : ls;
        acc += xz[((long)(b * L_ + lsrc)) * (2 * DI_) + d] * w[d * 4 + k];
    }
    float v = siluf(acc);
    out[idx] = v;
    outb[idx] = (bf16)v;
}

// ---------------------------------------------------------------------------
// LDS-staged chunked SSM scan, fwd+bwd fused (blockIdx.y = direction).
// ---------------------------------------------------------------------------
__global__ __launch_bounds__(256) void ssm_scan2(
    const float* __restrict__ xcF, const float* __restrict__ dtF, const float* __restrict__ dblF,
    const float* __restrict__ xcB, const float* __restrict__ dtB, const float* __restrict__ dblB,
    const float* __restrict__ xz,
    const float* __restrict__ AF, const float* __restrict__ DF,
    const float* __restrict__ AB, const float* __restrict__ DB,
    bf16* __restrict__ yF, bf16* __restrict__ yB)
{
    const int rev = blockIdx.y;
    const float* xc = rev ? xcB : xcF;
    const float* dt = rev ? dtB : dtF;
    const float* dbl = rev ? dblB : dblF;
    const float* Alog = rev ? AB : AF;
    const float* Dp = rev ? DB : DF;
    bf16* yout = rev ? yB : yF;

    const int t = threadIdx.x;
    const int n = t & 15;
    const int g = t >> 4;
    const int gb = blockIdx.x;               // 0..383
    const int b = gb / (DI_ / 16);
    const int d0 = (gb % (DI_ / 16)) * 16;
    const int d = d0 + g;

    __shared__ float dt_s[SCHUNK][16];
    __shared__ float xc_s[SCHUNK][16];
    __shared__ float z_s[SCHUNK][16];
    __shared__ float bm_s[SCHUNK][16];
    __shared__ float cm_s[SCHUNK][16];
    __shared__ float y_s[SCHUNK][16];

    const float a = -__expf(Alog[(size_t)d * 16 + n]);
    const float Dv = Dp[d];
    float h = 0.f;
    const size_t rowbase = (size_t)b * L_;

    for (int c0 = 0; c0 < L_; c0 += SCHUNK) {
        const int Tc = min(SCHUNK, L_ - c0);
        // ---- stage chunk (coalesced) ----
        for (int i = t; i < Tc * 16; i += 256) {
            int ll = i >> 4, dd = i & 15;
            int l = c0 + ll;
            size_t r = (rowbase + l) * DI_ + d0 + dd;
            dt_s[ll][dd] = dt[r];
            xc_s[ll][dd] = xc[r];
            int lz = rev ? (L_ - 1 - l) : l;
            z_s[ll][dd] = xz[(rowbase + lz) * (2 * DI_) + DI_ + d0 + dd];
            bm_s[ll][dd] = dbl[(rowbase + l) * 80 + 48 + dd];
            cm_s[ll][dd] = dbl[(rowbase + l) * 80 + 64 + dd];
        }
        __syncthreads();
        // ---- recurrence from LDS ----
#pragma unroll 4
        for (int ll = 0; ll < Tc; ll++) {
            float dtv = dt_s[ll][g];
            float xcv = xc_s[ll][g];
            float bm = bm_s[ll][n];
            float cm = cm_s[ll][n];
            h = __expf(dtv * a) * h + dtv * xcv * bm;
            float cc = h * cm;
            cc += __shfl_xor(cc, 1);
            cc += __shfl_xor(cc, 2);
            cc += __shfl_xor(cc, 4);
            cc += __shfl_xor(cc, 8);
            if (n == 0) {
                float yv = (cc + xcv * Dv) * siluf(z_s[ll][g]);
                y_s[ll][g] = yv;
            }
        }
        __syncthreads();
        // ---- writeout (coalesced, bf16) ----
        for (int i = t; i < Tc * 16; i += 256) {
            int ll = i >> 4, dd = i & 15;
            int l = c0 + ll;
            int lo = rev ? (L_ - 1 - l) : l;
            yout[(rowbase + lo) * DI_ + d0 + dd] = (bf16)y_s[ll][dd];
        }
        __syncthreads();
    }
}

__global__ void final_rms(const float* __restrict__ res, const float* __restrict__ h,
                          const float* __restrict__ w, float* __restrict__ out) {
    int b = blockIdx.x;
    long base = ((long)b * L_ + POS_) * D_;
    float v[3];
    float ss = 0.f;
#pragma unroll
    for (int i = 0; i < 3; i++) {
        int d = threadIdx.x + i * 256;
        float t = res[base + d] + h[base + d];
        v[i] = t;
        ss += t * t;
    }
#pragma unroll
    for (int off = 1; off < 64; off <<= 1) ss += __shfl_xor(ss, off);
    __shared__ float red[4];
    __shared__ float inv;
    if ((threadIdx.x & 63) == 0) red[threadIdx.x >> 6] = ss;
    __syncthreads();
    if (threadIdx.x == 0) {
        float s = red[0] + red[1] + red[2] + red[3];
        inv = rsqrtf(s / (float)D_ + 1e-5f);
    }
    __syncthreads();
    float iv = inv;
#pragma unroll
    for (int i = 0; i < 3; i++) {
        int d = threadIdx.x + i * 256;
        out[b * D_ + d] = v[i] * iv * w[d];
    }
}

// ---------------------------------------------------------------------------
extern "C" void kernel_launch(void* const* d_in, const int* in_sizes, int n_in,
                              void* d_out, int out_size, void* d_ws, size_t ws_size,
                              hipStream_t stream) {
    const float* img = (const float*)d_in[0];
    const float* patch_w = (const float*)d_in[1];
    const float* patch_b = (const float*)d_in[2];
    const float* cls_token = (const float*)d_in[3];
    const float* pos_embed = (const float*)d_in[4];
    const float* norm_w = (const float*)d_in[5];
    const float* in_proj_w = (const float*)d_in[6];
    const float* conv_f_w = (const float*)d_in[7];
    const float* conv_f_b = (const float*)d_in[8];
    const float* xproj_f_w = (const float*)d_in[9];
    const float* dt_f_w = (const float*)d_in[10];
    const float* dt_f_b = (const float*)d_in[11];
    const float* A_f_log = (const float*)d_in[12];
    const float* D_f = (const float*)d_in[13];
    const float* conv_b_w = (const float*)d_in[14];
    const float* conv_b_b = (const float*)d_in[15];
    const float* xproj_b_w = (const float*)d_in[16];
    const float* dt_b_w = (const float*)d_in[17];
    const float* dt_b_b = (const float*)d_in[18];
    const float* A_b_log = (const float*)d_in[19];
    const float* D_b = (const float*)d_in[20];
    const float* out_proj_w = (const float*)d_in[21];
    const float* norm_f_w = (const float*)d_in[22];
    const float* head_w = (const float*)d_in[23];
    const float* head_b = (const float*)d_in[24];

    char* p8 = (char*)d_ws;
    auto alloc = [&](size_t nb) { char* r = p8; p8 += (nb + 255) & ~(size_t)255; return r; };
    float* x    = (float*)alloc((size_t)M_ * D_ * 4);
    float* res  = (float*)alloc((size_t)M_ * D_ * 4);
    bf16*  hnb  = (bf16*) alloc((size_t)M_ * D_ * 2);
    float* xz   = (float*)alloc((size_t)M_ * 2 * DI_ * 4);
    float* xcf  = (float*)alloc((size_t)M_ * DI_ * 4);
    float* xcb  = (float*)alloc((size_t)M_ * DI_ * 4);
    bf16*  xcfb = (bf16*) alloc((size_t)M_ * DI_ * 2);
    bf16*  xcbb = (bf16*) alloc((size_t)M_ * DI_ * 2);
    float* dtf  = (float*)alloc((size_t)M_ * DI_ * 4);
    float* dtb  = (float*)alloc((size_t)M_ * DI_ * 4);
    bf16*  yfb  = (bf16*) alloc((size_t)M_ * DI_ * 2);
    bf16*  ybb  = (bf16*) alloc((size_t)M_ * DI_ * 2);
    float* dblf = (float*)alloc((size_t)M_ * 80 * 4);
    float* dblb = (float*)alloc((size_t)M_ * 80 * 4);
    bf16*  dblfb= (bf16*) alloc((size_t)M_ * 80 * 2);
    bf16*  dblbb= (bf16*) alloc((size_t)M_ * 80 * 2);
    float* clsv = (float*)alloc((size_t)B_ * D_ * 4);
    float* xtmp = dtf;   // alias: xtmp consumed (assemble) before layer 0 writes dtf

    // Split-K partial buffers, all aliased onto dead regions (no extra ws):
    //  - patch partials (8 x 1200 x 768 f32 = 29.49MB) live only before the
    //    layers: alias onto xz+xcf+xcb (14.79+7.40+7.40 = 29.59MB contiguous).
    //  - xproj partials (16 x 1204 x 80 f32 = 6.16MB) live between xproj gemm
    //    and its reduce; dtf (7.40MB) is dead there (written by dt gemm after).
    //  - out_proj partials (4 x 1204 x 768 f32 = 14.79MB) live after ssm_scan2
    //    has consumed dtf+dtb (exactly 14.79MB contiguous).
    float* patchP = xz;
    float* xprojP = dtf;
    float* outP   = dtf;

    // --- embed (split-K 8: 480 blocks vs 60; was 2.85% occupancy) ---
    gemm_patch_mfma<<<dim3(6, 10, 8), 256, 0, stream>>>(img, patch_w, patchP);
    reduce_sk2<<<dim3((1200 * 768 + 255) / 256, 1), 256, 0, stream>>>(
        patchP, (size_t)1200 * 768, 8, patch_b, xtmp, nullptr, nullptr, nullptr,
        1200 * 768, 768, 1);
    assemble<<<(B_ * L_ * D_ + 255) / 256, 256, 0, stream>>>(xtmp, cls_token, pos_embed, x, res);

    // --- layers ---
    for (int layer = 0; layer < 24; layer++) {
        const float* ipw = in_proj_w + (size_t)layer * 2 * DI_ * D_;
        const float* cfw = conv_f_w + (size_t)layer * DI_ * 4;
        const float* cfb = conv_f_b + (size_t)layer * DI_;
        const float* xfw = xproj_f_w + (size_t)layer * 80 * DI_;
        const float* dfw = dt_f_w + (size_t)layer * DI_ * 48;
        const float* dfb = dt_f_b + (size_t)layer * DI_;
        const float* afl = A_f_log + (size_t)layer * DI_ * 16;
        const float* df = D_f + (size_t)layer * DI_;
        const float* cbw = conv_b_w + (size_t)layer * DI_ * 4;
        const float* cbb = conv_b_b + (size_t)layer * DI_;
        const float* xbw = xproj_b_w + (size_t)layer * 80 * DI_;
        const float* dbw = dt_b_w + (size_t)layer * DI_ * 48;
        const float* dbb = dt_b_b + (size_t)layer * DI_;
        const float* abl = A_b_log + (size_t)layer * DI_ * 16;
        const float* db = D_b + (size_t)layer * DI_;
        const float* opw = out_proj_w + (size_t)layer * D_ * DI_;
        const float* nw = norm_w + (size_t)layer * D_;

        add_rms<<<M_, 256, 0, stream>>>(res, x, nw, hnb);
        gemm_mfma<<<dim3(24, 10, 1), 256, 0, stream>>>(
            hnb, hnb, D_, ipw, ipw, D_, nullptr, nullptr,
            xz, xz, nullptr, nullptr, 2 * DI_, M_, 2 * DI_, D_, 24, 0);
        conv_silu2<<<dim3((B_ * L_ * DI_ + 255) / 256, 2), 256, 0, stream>>>(
            xz, cfw, cfb, cbw, cbb, xcf, xcfb, xcb, xcbb);
        // xproj split-K 8: 160 blocks vs 20
        gemm_mfma_sk<<<dim3(1, 10, 16), 256, 0, stream>>>(
            xcfb, xcbb, DI_, xfw, xbw, DI_,
            xprojP, (size_t)M_ * 80, 80, M_, 80, 6, 8);
        reduce_sk2<<<dim3((M_ * 80 + 255) / 256, 2), 256, 0, stream>>>(
            xprojP, (size_t)M_ * 80, 8, nullptr,
            dblf, dblb, dblfb, dblbb, M_ * 80, 80, 0);
        gemm_mfma<<<dim3(12, 10, 2), 256, 0, stream>>>(
            dblfb, dblbb, 80, dfw, dbw, 48, dfb, dbb,
            dtf, dtb, nullptr, nullptr, DI_, M_, DI_, 48, 2, 2);
        ssm_scan2<<<dim3(384, 2), 256, 0, stream>>>(
            xcf, dtf, dblf, xcb, dtb, dblb, xz, afl, df, abl, db, yfb, ybb);
        // out_proj split-K 4: 240 blocks vs 60
        gemm_mfma_avg_sk<<<dim3(6, 10, 4), 256, 0, stream>>>(
            yfb, ybb, DI_, opw, DI_,
            outP, (size_t)M_ * D_, D_, M_, D_, 12, 4);
        reduce_sk2<<<dim3((M_ * D_ + 255) / 256, 1), 256, 0, stream>>>(
            outP, (size_t)M_ * D_, 4, nullptr,
            x, nullptr, nullptr, nullptr, M_ * D_, D_, 0);
    }

    // --- head ---
    final_rms<<<B_, 256, 0, stream>>>(res, x, norm_f_w, clsv);
    gemm_bt<<<dim3(16, 1), 256, 0, stream>>>(clsv, D_, head_w, D_, head_b,
                                             (float*)d_out, 1000, B_, 1000, D_, 1);
}

// Round 2
// 6487.150 us; speedup vs baseline: 1.6667x; 1.1312x over previous
//
#include <hip/hip_runtime.h>
#include <hip/hip_bf16.h>
#include <math.h>

#define B_ 4
#define L_ 301
#define D_ 768
#define DI_ 1536
#define NP_ 300
#define POS_ 150
#define M_ 1204
#define NC_ 5
#define CL_ 64

typedef __bf16 bf16;
typedef __attribute__((ext_vector_type(8))) __bf16 bf16x8;
typedef __attribute__((ext_vector_type(4))) float floatx4;

__device__ __forceinline__ float siluf(float x) { return x / (1.f + __expf(-x)); }
__device__ __forceinline__ float softplusf(float x) { return x > 20.f ? x : log1pf(__expf(x)); }

// ---------------------------------------------------------------------------
// MFMA bf16 GEMM, z-batched (blockIdx.z selects operand set 0/1):
// C[M,Nw] = act(A[M,K]bf16 @ W[Nw,K]f32^T + bias)
// 128x128 tile, BK=32, 256 thr (4 waves 2x2), 4x4 16x16x32 frags/wave.
// ---------------------------------------------------------------------------
__global__ __launch_bounds__(256) void gemm_mfma(
    const bf16* __restrict__ A0, const bf16* __restrict__ A1, int lda,
    const float* __restrict__ W0, const float* __restrict__ W1, int ldw,
    const float* __restrict__ bias0, const float* __restrict__ bias1,
    float* __restrict__ C0, float* __restrict__ C1,
    bf16* __restrict__ Cb0, bf16* __restrict__ Cb1, int ldc,
    int M, int Nw, int Kw, int Ksteps, int act)
{
    const int zz = blockIdx.z;
    const bf16* A = zz ? A1 : A0;
    const float* W = zz ? W1 : W0;
    const float* bias = zz ? bias1 : bias0;
    float* C = zz ? C1 : C0;
    bf16* Cb = zz ? Cb1 : Cb0;

    __shared__ bf16 As[128 * 32];
    __shared__ bf16 Ws[128 * 32];
    const int t = threadIdx.x;
    const int bm = blockIdx.y * 128;
    const int bn = blockIdx.x * 128;
    const int lane = t & 63;
    const int wid = t >> 6;
    const int wr = wid >> 1, wc = wid & 1;
    const int ar = t >> 2;
    const int ac = (t & 3) * 8;

    const bool fullNK = ((Nw & 127) == 0) && ((Kw & 31) == 0);

    floatx4 acc[4][4] = {};

    for (int ks = 0; ks < Ksteps; ks++) {
        const int k0 = ks * 32;
#pragma unroll
        for (int c2 = 0; c2 < 2; c2++) {
            int r = ar + c2 * 64;
            int gm = bm + r; if (gm >= M) gm = M - 1;
            const bf16* gp = A + (size_t)gm * lda + k0 + ac;
            __builtin_amdgcn_global_load_lds(
                (const __attribute__((address_space(1))) void*)gp,
                (__attribute__((address_space(3))) void*)(As + r * 32 + ac),
                16, 0, 0);
        }
#pragma unroll
        for (int c2 = 0; c2 < 2; c2++) {
            int r = ar + c2 * 64;
            int gn = bn + r;
            float vv[8];
            if (fullNK) {
                const floatx4* wp4 = (const floatx4*)(W + (size_t)gn * ldw + k0 + ac);
                floatx4 a4 = wp4[0], b4 = wp4[1];
#pragma unroll
                for (int e = 0; e < 4; e++) { vv[e] = a4[e]; vv[e + 4] = b4[e]; }
            } else {
                const float* wp = W + (size_t)gn * ldw + k0 + ac;
#pragma unroll
                for (int e = 0; e < 8; e++) {
                    int kk = k0 + ac + e;
                    vv[e] = (gn < Nw && kk < Kw) ? wp[e] : 0.f;
                }
            }
            bf16x8 pk;
#pragma unroll
            for (int e = 0; e < 8; e++) pk[e] = (bf16)vv[e];
            *(bf16x8*)(Ws + r * 32 + ac) = pk;
        }
        __syncthreads();
        const int ra = wr * 64 + (lane & 15);
        const int rb = wc * 64 + (lane & 15);
        const int kb = (lane >> 4) * 8;
        bf16x8 af[4], bfm[4];
#pragma unroll
        for (int i = 0; i < 4; i++)
            af[i] = *(const bf16x8*)(As + (ra + i * 16) * 32 + kb);
#pragma unroll
        for (int j = 0; j < 4; j++)
            bfm[j] = *(const bf16x8*)(Ws + (rb + j * 16) * 32 + kb);
#pragma unroll
        for (int i = 0; i < 4; i++)
#pragma unroll
            for (int j = 0; j < 4; j++)
                acc[i][j] = __builtin_amdgcn_mfma_f32_16x16x32_bf16(af[i], bfm[j], acc[i][j], 0, 0, 0);
        __syncthreads();
    }
#pragma unroll
    for (int i = 0; i < 4; i++) {
#pragma unroll
        for (int j = 0; j < 4; j++) {
            int n = bn + wc * 64 + j * 16 + (lane & 15);
            if (n >= Nw) continue;
            float bv = (act >= 1) ? bias[n] : 0.f;
#pragma unroll
            for (int r = 0; r < 4; r++) {
                int m = bm + wr * 64 + i * 16 + (lane >> 4) * 4 + r;
                if (m >= M) continue;
                float v = acc[i][j][r] + bv;
                if (act == 2) v = softplusf(v);
                C[(size_t)m * ldc + n] = v;
                if (Cb) Cb[(size_t)m * ldc + n] = (bf16)v;
            }
        }
    }
}

// ---------------------------------------------------------------------------
// Split-K MFMA GEMM (2-dir): blockIdx.z = dir*SK + chunk. Writes f32 partial
// C-tiles to Cp[z]; a reduce kernel sums them.
// ---------------------------------------------------------------------------
__global__ __launch_bounds__(256) void gemm_mfma_sk(
    const bf16* __restrict__ A0, const bf16* __restrict__ A1, int lda,
    const float* __restrict__ W0, const float* __restrict__ W1, int ldw,
    float* __restrict__ Cp, size_t chunkStride, int ldc,
    int M, int Nw, int KstepsPer, int SK)
{
    const int z = blockIdx.z;
    const int dir = z / SK;
    const int chunk = z % SK;
    const bf16* A = dir ? A1 : A0;
    const float* W = dir ? W1 : W0;
    float* C = Cp + (size_t)z * chunkStride;

    __shared__ bf16 As[128 * 32];
    __shared__ bf16 Ws[128 * 32];
    const int t = threadIdx.x;
    const int bm = blockIdx.y * 128;
    const int bn = blockIdx.x * 128;
    const int lane = t & 63;
    const int wid = t >> 6;
    const int wr = wid >> 1, wc = wid & 1;
    const int ar = t >> 2;
    const int ac = (t & 3) * 8;

    floatx4 acc[4][4] = {};

    for (int ks = 0; ks < KstepsPer; ks++) {
        const int k0 = (chunk * KstepsPer + ks) * 32;
#pragma unroll
        for (int c2 = 0; c2 < 2; c2++) {
            int r = ar + c2 * 64;
            int gm = bm + r; if (gm >= M) gm = M - 1;
            const bf16* gp = A + (size_t)gm * lda + k0 + ac;
            __builtin_amdgcn_global_load_lds(
                (const __attribute__((address_space(1))) void*)gp,
                (__attribute__((address_space(3))) void*)(As + r * 32 + ac),
                16, 0, 0);
        }
#pragma unroll
        for (int c2 = 0; c2 < 2; c2++) {
            int r = ar + c2 * 64;
            int gn = bn + r;
            bf16x8 pk;
            if (gn < Nw) {
                const floatx4* wp4 = (const floatx4*)(W + (size_t)gn * ldw + k0 + ac);
                floatx4 a4 = wp4[0], b4 = wp4[1];
#pragma unroll
                for (int e = 0; e < 4; e++) { pk[e] = (bf16)a4[e]; pk[e + 4] = (bf16)b4[e]; }
            } else {
#pragma unroll
                for (int e = 0; e < 8; e++) pk[e] = (bf16)0.f;
            }
            *(bf16x8*)(Ws + r * 32 + ac) = pk;
        }
        __syncthreads();
        const int ra = wr * 64 + (lane & 15);
        const int rb = wc * 64 + (lane & 15);
        const int kb = (lane >> 4) * 8;
        bf16x8 af[4], bfm[4];
#pragma unroll
        for (int i = 0; i < 4; i++)
            af[i] = *(const bf16x8*)(As + (ra + i * 16) * 32 + kb);
#pragma unroll
        for (int j = 0; j < 4; j++)
            bfm[j] = *(const bf16x8*)(Ws + (rb + j * 16) * 32 + kb);
#pragma unroll
        for (int i = 0; i < 4; i++)
#pragma unroll
            for (int j = 0; j < 4; j++)
                acc[i][j] = __builtin_amdgcn_mfma_f32_16x16x32_bf16(af[i], bfm[j], acc[i][j], 0, 0, 0);
        __syncthreads();
    }
#pragma unroll
    for (int i = 0; i < 4; i++) {
#pragma unroll
        for (int j = 0; j < 4; j++) {
            int n = bn + wc * 64 + j * 16 + (lane & 15);
            if (n >= Nw) continue;
#pragma unroll
            for (int r = 0; r < 4; r++) {
                int m = bm + wr * 64 + i * 16 + (lane >> 4) * 4 + r;
                if (m >= M) continue;
                C[(size_t)m * ldc + n] = acc[i][j][r];
            }
        }
    }
}

// ---------------------------------------------------------------------------
// out_proj split-K GEMM: A = bf16(0.5*(Af+Ab)) merged during staging.
// ---------------------------------------------------------------------------
__global__ __launch_bounds__(256) void gemm_mfma_avg_sk(
    const bf16* __restrict__ Af, const bf16* __restrict__ Ab, int lda,
    const float* __restrict__ W, int ldw,
    float* __restrict__ Cp, size_t chunkStride, int ldc,
    int M, int Nw, int KstepsPer, int SK)
{
    const int chunk = blockIdx.z;
    float* C = Cp + (size_t)chunk * chunkStride;

    __shared__ bf16 As[128 * 32];
    __shared__ bf16 Ws[128 * 32];
    const int t = threadIdx.x;
    const int bm = blockIdx.y * 128;
    const int bn = blockIdx.x * 128;
    const int lane = t & 63;
    const int wid = t >> 6;
    const int wr = wid >> 1, wc = wid & 1;
    const int ar = t >> 2;
    const int ac = (t & 3) * 8;

    floatx4 acc[4][4] = {};

    for (int ks = 0; ks < KstepsPer; ks++) {
        const int k0 = (chunk * KstepsPer + ks) * 32;
#pragma unroll
        for (int c2 = 0; c2 < 2; c2++) {
            int r = ar + c2 * 64;
            int gm = bm + r; if (gm >= M) gm = M - 1;
            bf16x8 a8 = *(const bf16x8*)(Af + (size_t)gm * lda + k0 + ac);
            bf16x8 b8 = *(const bf16x8*)(Ab + (size_t)gm * lda + k0 + ac);
            bf16x8 pk;
#pragma unroll
            for (int e = 0; e < 8; e++)
                pk[e] = (bf16)(0.5f * ((float)a8[e] + (float)b8[e]));
            *(bf16x8*)(As + r * 32 + ac) = pk;
        }
#pragma unroll
        for (int c2 = 0; c2 < 2; c2++) {
            int r = ar + c2 * 64;
            int gn = bn + r;
            const floatx4* wp4 = (const floatx4*)(W + (size_t)gn * ldw + k0 + ac);
            floatx4 a4 = wp4[0], b4 = wp4[1];
            bf16x8 pk;
#pragma unroll
            for (int e = 0; e < 4; e++) { pk[e] = (bf16)a4[e]; pk[e + 4] = (bf16)b4[e]; }
            *(bf16x8*)(Ws + r * 32 + ac) = pk;
        }
        __syncthreads();
        const int ra = wr * 64 + (lane & 15);
        const int rb = wc * 64 + (lane & 15);
        const int kb = (lane >> 4) * 8;
        bf16x8 af[4], bfm[4];
#pragma unroll
        for (int i = 0; i < 4; i++)
            af[i] = *(const bf16x8*)(As + (ra + i * 16) * 32 + kb);
#pragma unroll
        for (int j = 0; j < 4; j++)
            bfm[j] = *(const bf16x8*)(Ws + (rb + j * 16) * 32 + kb);
#pragma unroll
        for (int i = 0; i < 4; i++)
#pragma unroll
            for (int j = 0; j < 4; j++)
                acc[i][j] = __builtin_amdgcn_mfma_f32_16x16x32_bf16(af[i], bfm[j], acc[i][j], 0, 0, 0);
        __syncthreads();
    }
#pragma unroll
    for (int i = 0; i < 4; i++) {
#pragma unroll
        for (int j = 0; j < 4; j++) {
            int n = bn + wc * 64 + j * 16 + (lane & 15);
            if (n >= Nw) continue;
#pragma unroll
            for (int r = 0; r < 4; r++) {
                int m = bm + wr * 64 + i * 16 + (lane >> 4) * 4 + r;
                if (m >= M) continue;
                C[(size_t)m * ldc + n] = acc[i][j][r];
            }
        }
    }
}

// ---------------------------------------------------------------------------
// Split-K reduce: C = act(sum_chunks Cp + bias); optional bf16 mirror.
// ---------------------------------------------------------------------------
__global__ void reduce_sk2(const float* __restrict__ Cp, size_t chunkStride, int SK,
                           const float* __restrict__ bias0,
                           float* __restrict__ C0, float* __restrict__ C1,
                           bf16* __restrict__ Cb0, bf16* __restrict__ Cb1,
                           int total, int ldn, int act)
{
    const int dir = blockIdx.y;
    const float* P = Cp + (size_t)dir * SK * chunkStride;
    float* C = dir ? C1 : C0;
    bf16* Cb = dir ? Cb1 : Cb0;
    int idx = blockIdx.x * 256 + threadIdx.x;
    if (idx >= total) return;
    float s = 0.f;
    for (int c = 0; c < SK; c++) s += P[(size_t)c * chunkStride + idx];
    if (act >= 1) s += bias0[idx % ldn];
    if (act == 2) s = softplusf(s);
    C[idx] = s;
    if (Cb) Cb[idx] = (bf16)s;
}

// ---------------------------------------------------------------------------
// Patch-embed MFMA GEMM, split-K over blockIdx.z (SK=8, 48 ksteps/chunk).
// ---------------------------------------------------------------------------
__global__ __launch_bounds__(256) void gemm_patch_mfma(
    const float* __restrict__ img, const float* __restrict__ W,
    float* __restrict__ Cp)
{
    __shared__ bf16 As[128 * 32];
    __shared__ bf16 Ws[128 * 32];
    const int t = threadIdx.x;
    const int bm = blockIdx.y * 128;
    const int bn = blockIdx.x * 128;
    const int chunk = blockIdx.z;
    const int lane = t & 63;
    const int wid = t >> 6;
    const int wr = wid >> 1, wc = wid & 1;
    const int ar = t >> 2;
    const int ac = (t & 3) * 8;
    const int M = 1200, ldw = 12288, ldc = 768;
    float* C = Cp + (size_t)chunk * M * ldc;

    const float* abase[2];
#pragma unroll
    for (int c2 = 0; c2 < 2; c2++) {
        int gm = bm + ar + c2 * 64; if (gm >= M) gm = M - 1;
        int b = gm / 300, rem = gm % 300;
        int gi = rem / 15, gj = rem % 15;
        abase[c2] = img + ((size_t)(b * 3) * 1280 + gi * 64) * 960 + gj * 64;
    }

    floatx4 acc[4][4] = {};

    for (int ks = 0; ks < 48; ks++) {
        const int k0 = (chunk * 48 + ks) * 32;
        const int k = k0 + ac;
        const int q = k & 63, p = (k >> 6) & 63, c = k >> 12;
#pragma unroll
        for (int c2 = 0; c2 < 2; c2++) {
            int r = ar + c2 * 64;
            const float* ip = abase[c2] + ((size_t)c * 1280 + p) * 960 + q;
            const floatx4* ip4 = (const floatx4*)ip;
            floatx4 a4 = ip4[0], b4 = ip4[1];
            bf16x8 pk;
#pragma unroll
            for (int e = 0; e < 4; e++) { pk[e] = (bf16)a4[e]; pk[e + 4] = (bf16)b4[e]; }
            *(bf16x8*)(As + r * 32 + ac) = pk;
        }
#pragma unroll
        for (int c2 = 0; c2 < 2; c2++) {
            int r = ar + c2 * 64;
            int gn = bn + r;
            const floatx4* wp4 = (const floatx4*)(W + (size_t)gn * ldw + k);
            floatx4 a4 = wp4[0], b4 = wp4[1];
            bf16x8 pk;
#pragma unroll
            for (int e = 0; e < 4; e++) { pk[e] = (bf16)a4[e]; pk[e + 4] = (bf16)b4[e]; }
            *(bf16x8*)(Ws + r * 32 + ac) = pk;
        }
        __syncthreads();
        const int ra = wr * 64 + (lane & 15);
        const int rb = wc * 64 + (lane & 15);
        const int kb = (lane >> 4) * 8;
        bf16x8 af[4], bfm[4];
#pragma unroll
        for (int i = 0; i < 4; i++)
            af[i] = *(const bf16x8*)(As + (ra + i * 16) * 32 + kb);
#pragma unroll
        for (int j = 0; j < 4; j++)
            bfm[j] = *(const bf16x8*)(Ws + (rb + j * 16) * 32 + kb);
#pragma unroll
        for (int i = 0; i < 4; i++)
#pragma unroll
            for (int j = 0; j < 4; j++)
                acc[i][j] = __builtin_amdgcn_mfma_f32_16x16x32_bf16(af[i], bfm[j], acc[i][j], 0, 0, 0);
        __syncthreads();
    }
#pragma unroll
    for (int i = 0; i < 4; i++) {
#pragma unroll
        for (int j = 0; j < 4; j++) {
            int n = bn + wc * 64 + j * 16 + (lane & 15);
#pragma unroll
            for (int r = 0; r < 4; r++) {
                int m = bm + wr * 64 + i * 16 + (lane >> 4) * 4 + r;
                if (m >= M) continue;
                C[(size_t)m * ldc + n] = acc[i][j][r];
            }
        }
    }
}

// ---------------------------------------------------------------------------
// fp32 GEMM for the tiny head matmul.
// ---------------------------------------------------------------------------
__global__ void gemm_bt(const float* __restrict__ A, int lda,
                        const float* __restrict__ W, int ldw,
                        const float* __restrict__ bias,
                        float* __restrict__ C, int ldc,
                        int M, int N, int K, int act) {
    __shared__ float As[16][68];
    __shared__ float Ws[16][68];
    const int tid = threadIdx.x;
    const int bm = blockIdx.y * 64;
    const int bn = blockIdx.x * 64;
    const int tx = tid & 15, ty = tid >> 4;
    float acc[4][4] = {};
    const int lk = tid & 15;
    const int lm = tid >> 4;
    for (int k0 = 0; k0 < K; k0 += 16) {
        const int ak = k0 + lk;
#pragma unroll
        for (int i = 0; i < 4; i++) {
            int m = bm + lm + i * 16;
            float v = 0.f;
            if (m < M && ak < K) v = A[(long)m * lda + ak];
            As[lk][lm + i * 16] = v;
        }
#pragma unroll
        for (int i = 0; i < 4; i++) {
            int n = bn + lm + i * 16;
            float v = 0.f;
            if (n < N && ak < K) v = W[(long)n * ldw + ak];
            Ws[lk][lm + i * 16] = v;
        }
        __syncthreads();
#pragma unroll
        for (int kk = 0; kk < 16; kk++) {
            float a[4], w[4];
#pragma unroll
            for (int i = 0; i < 4; i++) a[i] = As[kk][ty * 4 + i];
#pragma unroll
            for (int j = 0; j < 4; j++) w[j] = Ws[kk][tx * 4 + j];
#pragma unroll
            for (int i = 0; i < 4; i++)
#pragma unroll
                for (int j = 0; j < 4; j++) acc[i][j] += a[i] * w[j];
        }
        __syncthreads();
    }
#pragma unroll
    for (int i = 0; i < 4; i++) {
        int m = bm + ty * 4 + i;
        if (m >= M) continue;
#pragma unroll
        for (int j = 0; j < 4; j++) {
            int n = bn + tx * 4 + j;
            if (n >= N) continue;
            float v = acc[i][j];
            if (act >= 1) v += bias[n];
            C[(long)m * ldc + n] = v;
        }
    }
}

// ---------------------------------------------------------------------------
__global__ void assemble(const float* __restrict__ xt, const float* __restrict__ cls,
                         const float* __restrict__ pos, float* __restrict__ x,
                         float* __restrict__ res) {
    int idx = blockIdx.x * 256 + threadIdx.x;
    if (idx >= B_ * L_ * D_) return;
    int d = idx % D_;
    int l = (idx / D_) % L_;
    int b = idx / (D_ * L_);
    float v;
    if (l == POS_) {
        v = cls[d];
    } else {
        int p = (l < POS_) ? l : l - 1;
        v = xt[((long)b * NP_ + p) * D_ + d];
    }
    x[idx] = v + pos[l * D_ + d];
    res[idx] = 0.f;
}

// res += h ; hn = bf16(rms(res) * w)
__global__ void add_rms(float* __restrict__ res, const float* __restrict__ h,
                        const float* __restrict__ w, bf16* __restrict__ hn) {
    int row = blockIdx.x;
    float* rr = res + (long)row * D_;
    const float* hr = h + (long)row * D_;
    float v[3];
    float ss = 0.f;
#pragma unroll
    for (int i = 0; i < 3; i++) {
        int d = threadIdx.x + i * 256;
        float t = rr[d] + hr[d];
        v[i] = t;
        ss += t * t;
    }
#pragma unroll
    for (int off = 1; off < 64; off <<= 1) ss += __shfl_xor(ss, off);
    __shared__ float red[4];
    __shared__ float inv;
    if ((threadIdx.x & 63) == 0) red[threadIdx.x >> 6] = ss;
    __syncthreads();
    if (threadIdx.x == 0) {
        float s = red[0] + red[1] + red[2] + red[3];
        inv = rsqrtf(s / (float)D_ + 1e-5f);
    }
    __syncthreads();
    float iv = inv;
#pragma unroll
    for (int i = 0; i < 3; i++) {
        int d = threadIdx.x + i * 256;
        rr[d] = v[i];
        hn[(long)row * D_ + d] = (bf16)(v[i] * iv * w[d]);
    }
}

// Depthwise causal conv (K=4) + silu, both directions in one dispatch.
__global__ void conv_silu2(const float* __restrict__ xz,
                           const float* __restrict__ wf, const float* __restrict__ bf_,
                           const float* __restrict__ wb, const float* __restrict__ bb_,
                           float* __restrict__ of, bf16* __restrict__ ofb,
                           float* __restrict__ ob, bf16* __restrict__ obb) {
    int idx = blockIdx.x * 256 + threadIdx.x;
    if (idx >= B_ * L_ * DI_) return;
    const int rev = blockIdx.y;
    const float* w = rev ? wb : wf;
    const float* bias = rev ? bb_ : bf_;
    float* out = rev ? ob : of;
    bf16* outb = rev ? obb : ofb;
    int d = idx % DI_;
    int l = (idx / DI_) % L_;
    int b = idx / (DI_ * L_);
    float acc = bias[d];
#pragma unroll
    for (int k = 0; k < 4; k++) {
        int ls = l - 3 + k;
        if (ls < 0) continue;
        int lsrc = rev ? (L_ - 1 - ls) : ls;
        acc += xz[((long)(b * L_ + lsrc)) * (2 * DI_) + d] * w[d * 4 + k];
    }
    float v = siluf(acc);
    out[idx] = v;
    outb[idx] = (bf16)v;
}

// ---------------------------------------------------------------------------
// Chunked two-pass parallel SSM scan.
// The recurrence h_t = exp(dt_t*a)*h_{t-1} + dt_t*xc_t*B_t is a linear scan;
// since a is time-constant, a chunk's transition product is exp(a*sum(dt)).
// Pass 1: chunks 0..NC-2 in parallel compute local scans (h from 0) ->
//         Hend[c] and Aprod[c] = exp(a*sum dt). Needs only dt/xc/B.
// Pass 2: all NC chunks in parallel: combine carries (<=4 fma steps), then
//         run the full recurrence + y output over 64 steps instead of 301.
// Serial depth 301 -> 64; grid 768 -> 3840 blocks (LDS-capped 24 waves/CU).
// ---------------------------------------------------------------------------
__global__ __launch_bounds__(256) void ssm_p1(
    const float* __restrict__ xcF, const float* __restrict__ dtF, const float* __restrict__ dblF,
    const float* __restrict__ xcB, const float* __restrict__ dtB, const float* __restrict__ dblB,
    const float* __restrict__ AF, const float* __restrict__ AB,
    float* __restrict__ Hend, float* __restrict__ Aprod)
{
    const int rev = blockIdx.y;
    const int c = blockIdx.z;                // 0..NC_-2
    const float* xc = rev ? xcB : xcF;
    const float* dt = rev ? dtB : dtF;
    const float* dbl = rev ? dblB : dblF;
    const float* Alog = rev ? AB : AF;

    const int t = threadIdx.x;
    const int n = t & 15;
    const int g = t >> 4;
    const int gb = blockIdx.x;               // 0..383
    const int b = gb / (DI_ / 16);
    const int d0 = (gb % (DI_ / 16)) * 16;
    const int d = d0 + g;

    __shared__ float dt_s[CL_][16];
    __shared__ float xc_s[CL_][16];
    __shared__ float bm_s[CL_][16];

    const float a = -__expf(Alog[(size_t)d * 16 + n]);
    const size_t rowbase = (size_t)b * L_;
    const int c0 = c * CL_;                  // Tc == CL_ always (c <= NC_-2)

    for (int i = t; i < CL_ * 16; i += 256) {
        int ll = i >> 4, dd = i & 15;
        int l = c0 + ll;
        size_t r = (rowbase + l) * DI_ + d0 + dd;
        dt_s[ll][dd] = dt[r];
        xc_s[ll][dd] = xc[r];
        bm_s[ll][dd] = dbl[(rowbase + l) * 80 + 48 + dd];
    }
    __syncthreads();

    float h = 0.f, sdt = 0.f;
#pragma unroll 4
    for (int ll = 0; ll < CL_; ll++) {
        float dtv = dt_s[ll][g];
        float xcv = xc_s[ll][g];
        float bm = bm_s[ll][n];
        h = __expf(dtv * a) * h + dtv * xcv * bm;
        sdt += dtv;
    }
    size_t o = (((size_t)rev * (NC_ - 1) + c) * 384 + gb) * 256 + t;
    Hend[o] = h;
    Aprod[o] = __expf(a * sdt);
}

__global__ __launch_bounds__(256) void ssm_p2(
    const float* __restrict__ xcF, const float* __restrict__ dtF, const float* __restrict__ dblF,
    const float* __restrict__ xcB, const float* __restrict__ dtB, const float* __restrict__ dblB,
    const float* __restrict__ xz,
    const float* __restrict__ AF, const float* __restrict__ DF,
    const float* __restrict__ AB, const float* __restrict__ DB,
    const float* __restrict__ Hend, const float* __restrict__ Aprod,
    bf16* __restrict__ yF, bf16* __restrict__ yB)
{
    const int rev = blockIdx.y;
    const int c = blockIdx.z;                // 0..NC_-1
    const float* xc = rev ? xcB : xcF;
    const float* dt = rev ? dtB : dtF;
    const float* dbl = rev ? dblB : dblF;
    const float* Alog = rev ? AB : AF;
    const float* Dp = rev ? DB : DF;
    bf16* yout = rev ? yB : yF;

    const int t = threadIdx.x;
    const int n = t & 15;
    const int g = t >> 4;
    const int gb = blockIdx.x;               // 0..383
    const int b = gb / (DI_ / 16);
    const int d0 = (gb % (DI_ / 16)) * 16;
    const int d = d0 + g;

    __shared__ float dt_s[CL_][16];
    __shared__ float xc_s[CL_][16];
    __shared__ float z_s[CL_][16];
    __shared__ float bm_s[CL_][16];
    __shared__ float cm_s[CL_][16];
    __shared__ float y_s[CL_][16];

    const float a = -__expf(Alog[(size_t)d * 16 + n]);
    const float Dv = Dp[d];
    const size_t rowbase = (size_t)b * L_;
    const int c0 = c * CL_;
    const int Tc = min(CL_, L_ - c0);

    // ---- stage chunk (coalesced) ----
    for (int i = t; i < Tc * 16; i += 256) {
        int ll = i >> 4, dd = i & 15;
        int l = c0 + ll;
        size_t r = (rowbase + l) * DI_ + d0 + dd;
        dt_s[ll][dd] = dt[r];
        xc_s[ll][dd] = xc[r];
        int lz = rev ? (L_ - 1 - l) : l;
        z_s[ll][dd] = xz[(rowbase + lz) * (2 * DI_) + DI_ + d0 + dd];
        bm_s[ll][dd] = dbl[(rowbase + l) * 80 + 48 + dd];
        cm_s[ll][dd] = dbl[(rowbase + l) * 80 + 64 + dd];
    }

    // ---- carry combine: h_in = scan of earlier chunks' (Aprod, Hend) ----
    float h = 0.f;
    for (int j = 0; j < c; j++) {
        size_t o = (((size_t)rev * (NC_ - 1) + j) * 384 + gb) * 256 + t;
        h = Aprod[o] * h + Hend[o];
    }
    __syncthreads();

    // ---- recurrence from LDS ----
#pragma unroll 4
    for (int ll = 0; ll < Tc; ll++) {
        float dtv = dt_s[ll][g];
        float xcv = xc_s[ll][g];
        float bm = bm_s[ll][n];
        float cm = cm_s[ll][n];
        h = __expf(dtv * a) * h + dtv * xcv * bm;
        float cc = h * cm;
        cc += __shfl_xor(cc, 1);
        cc += __shfl_xor(cc, 2);
        cc += __shfl_xor(cc, 4);
        cc += __shfl_xor(cc, 8);
        if (n == 0) {
            float yv = (cc + xcv * Dv) * siluf(z_s[ll][g]);
            y_s[ll][g] = yv;
        }
    }
    __syncthreads();

    // ---- writeout (coalesced, bf16) ----
    for (int i = t; i < Tc * 16; i += 256) {
        int ll = i >> 4, dd = i & 15;
        int l = c0 + ll;
        int lo = rev ? (L_ - 1 - l) : l;
        yout[(rowbase + lo) * DI_ + d0 + dd] = (bf16)y_s[ll][dd];
    }
}

__global__ void final_rms(const float* __restrict__ res, const float* __restrict__ h,
                          const float* __restrict__ w, float* __restrict__ out) {
    int b = blockIdx.x;
    long base = ((long)b * L_ + POS_) * D_;
    float v[3];
    float ss = 0.f;
#pragma unroll
    for (int i = 0; i < 3; i++) {
        int d = threadIdx.x + i * 256;
        float t = res[base + d] + h[base + d];
        v[i] = t;
        ss += t * t;
    }
#pragma unroll
    for (int off = 1; off < 64; off <<= 1) ss += __shfl_xor(ss, off);
    __shared__ float red[4];
    __shared__ float inv;
    if ((threadIdx.x & 63) == 0) red[threadIdx.x >> 6] = ss;
    __syncthreads();
    if (threadIdx.x == 0) {
        float s = red[0] + red[1] + red[2] + red[3];
        inv = rsqrtf(s / (float)D_ + 1e-5f);
    }
    __syncthreads();
    float iv = inv;
#pragma unroll
    for (int i = 0; i < 3; i++) {
        int d = threadIdx.x + i * 256;
        out[b * D_ + d] = v[i] * iv * w[d];
    }
}

// ---------------------------------------------------------------------------
extern "C" void kernel_launch(void* const* d_in, const int* in_sizes, int n_in,
                              void* d_out, int out_size, void* d_ws, size_t ws_size,
                              hipStream_t stream) {
    const float* img = (const float*)d_in[0];
    const float* patch_w = (const float*)d_in[1];
    const float* patch_b = (const float*)d_in[2];
    const float* cls_token = (const float*)d_in[3];
    const float* pos_embed = (const float*)d_in[4];
    const float* norm_w = (const float*)d_in[5];
    const float* in_proj_w = (const float*)d_in[6];
    const float* conv_f_w = (const float*)d_in[7];
    const float* conv_f_b = (const float*)d_in[8];
    const float* xproj_f_w = (const float*)d_in[9];
    const float* dt_f_w = (const float*)d_in[10];
    const float* dt_f_b = (const float*)d_in[11];
    const float* A_f_log = (const float*)d_in[12];
    const float* D_f = (const float*)d_in[13];
    const float* conv_b_w = (const float*)d_in[14];
    const float* conv_b_b = (const float*)d_in[15];
    const float* xproj_b_w = (const float*)d_in[16];
    const float* dt_b_w = (const float*)d_in[17];
    const float* dt_b_b = (const float*)d_in[18];
    const float* A_b_log = (const float*)d_in[19];
    const float* D_b = (const float*)d_in[20];
    const float* out_proj_w = (const float*)d_in[21];
    const float* norm_f_w = (const float*)d_in[22];
    const float* head_w = (const float*)d_in[23];
    const float* head_b = (const float*)d_in[24];

    char* p8 = (char*)d_ws;
    auto alloc = [&](size_t nb) { char* r = p8; p8 += (nb + 255) & ~(size_t)255; return r; };
    float* x    = (float*)alloc((size_t)M_ * D_ * 4);
    float* res  = (float*)alloc((size_t)M_ * D_ * 4);
    bf16*  hnb  = (bf16*) alloc((size_t)M_ * D_ * 2);
    float* xz   = (float*)alloc((size_t)M_ * 2 * DI_ * 4);
    float* xcf  = (float*)alloc((size_t)M_ * DI_ * 4);
    float* xcb  = (float*)alloc((size_t)M_ * DI_ * 4);
    bf16*  xcfb = (bf16*) alloc((size_t)M_ * DI_ * 2);
    bf16*  xcbb = (bf16*) alloc((size_t)M_ * DI_ * 2);
    float* dtf  = (float*)alloc((size_t)M_ * DI_ * 4);
    float* dtb  = (float*)alloc((size_t)M_ * DI_ * 4);
    bf16*  yfb  = (bf16*) alloc((size_t)M_ * DI_ * 2);
    bf16*  ybb  = (bf16*) alloc((size_t)M_ * DI_ * 2);
    float* dblf = (float*)alloc((size_t)M_ * 80 * 4);
    float* dblb = (float*)alloc((size_t)M_ * 80 * 4);
    bf16*  dblfb= (bf16*) alloc((size_t)M_ * 80 * 2);
    bf16*  dblbb= (bf16*) alloc((size_t)M_ * 80 * 2);
    float* clsv = (float*)alloc((size_t)B_ * D_ * 4);
    // chunked-scan carry buffers: [2 dir][NC-1][384 gb][256] f32 = 3.15MB each
    float* hend = (float*)alloc((size_t)2 * (NC_ - 1) * 384 * 256 * 4);
    float* aprd = (float*)alloc((size_t)2 * (NC_ - 1) * 384 * 256 * 4);
    float* xtmp = dtf;   // alias: xtmp consumed (assemble) before layer 0 writes dtf

    // Split-K partial buffers, aliased onto dead regions:
    //  - patch partials (8 x 1200 x 768 f32) alias xz+xcf+xcb (29.59MB contiguous).
    //  - xproj partials (16 x 1204 x 80 f32) alias dtf (dead until dt gemm).
    //  - out_proj partials (4 x 1204 x 768 f32) alias dtf+dtb (dead after ssm).
    float* patchP = xz;
    float* xprojP = dtf;
    float* outP   = dtf;

    // --- embed (split-K 8: 480 blocks) ---
    gemm_patch_mfma<<<dim3(6, 10, 8), 256, 0, stream>>>(img, patch_w, patchP);
    reduce_sk2<<<dim3((1200 * 768 + 255) / 256, 1), 256, 0, stream>>>(
        patchP, (size_t)1200 * 768, 8, patch_b, xtmp, nullptr, nullptr, nullptr,
        1200 * 768, 768, 1);
    assemble<<<(B_ * L_ * D_ + 255) / 256, 256, 0, stream>>>(xtmp, cls_token, pos_embed, x, res);

    // --- layers ---
    for (int layer = 0; layer < 24; layer++) {
        const float* ipw = in_proj_w + (size_t)layer * 2 * DI_ * D_;
        const float* cfw = conv_f_w + (size_t)layer * DI_ * 4;
        const float* cfb = conv_f_b + (size_t)layer * DI_;
        const float* xfw = xproj_f_w + (size_t)layer * 80 * DI_;
        const float* dfw = dt_f_w + (size_t)layer * DI_ * 48;
        const float* dfb = dt_f_b + (size_t)layer * DI_;
        const float* afl = A_f_log + (size_t)layer * DI_ * 16;
        const float* df = D_f + (size_t)layer * DI_;
        const float* cbw = conv_b_w + (size_t)layer * DI_ * 4;
        const float* cbb = conv_b_b + (size_t)layer * DI_;
        const float* xbw = xproj_b_w + (size_t)layer * 80 * DI_;
        const float* dbw = dt_b_w + (size_t)layer * DI_ * 48;
        const float* dbb = dt_b_b + (size_t)layer * DI_;
        const float* abl = A_b_log + (size_t)layer * DI_ * 16;
        const float* db = D_b + (size_t)layer * DI_;
        const float* opw = out_proj_w + (size_t)layer * D_ * DI_;
        const float* nw = norm_w + (size_t)layer * D_;

        add_rms<<<M_, 256, 0, stream>>>(res, x, nw, hnb);
        gemm_mfma<<<dim3(24, 10, 1), 256, 0, stream>>>(
            hnb, hnb, D_, ipw, ipw, D_, nullptr, nullptr,
            xz, xz, nullptr, nullptr, 2 * DI_, M_, 2 * DI_, D_, 24, 0);
        conv_silu2<<<dim3((B_ * L_ * DI_ + 255) / 256, 2), 256, 0, stream>>>(
            xz, cfw, cfb, cbw, cbb, xcf, xcfb, xcb, xcbb);
        // xproj split-K 8: 160 blocks
        gemm_mfma_sk<<<dim3(1, 10, 16), 256, 0, stream>>>(
            xcfb, xcbb, DI_, xfw, xbw, DI_,
            xprojP, (size_t)M_ * 80, 80, M_, 80, 6, 8);
        reduce_sk2<<<dim3((M_ * 80 + 255) / 256, 2), 256, 0, stream>>>(
            xprojP, (size_t)M_ * 80, 8, nullptr,
            dblf, dblb, dblfb, dblbb, M_ * 80, 80, 0);
        gemm_mfma<<<dim3(12, 10, 2), 256, 0, stream>>>(
            dblfb, dblbb, 80, dfw, dbw, 48, dfb, dbb,
            dtf, dtb, nullptr, nullptr, DI_, M_, DI_, 48, 2, 2);
        // chunked two-pass scan (serial depth 301 -> 64)
        ssm_p1<<<dim3(384, 2, NC_ - 1), 256, 0, stream>>>(
            xcf, dtf, dblf, xcb, dtb, dblb, afl, abl, hend, aprd);
        ssm_p2<<<dim3(384, 2, NC_), 256, 0, stream>>>(
            xcf, dtf, dblf, xcb, dtb, dblb, xz, afl, df, abl, db,
            hend, aprd, yfb, ybb);
        // out_proj split-K 4: 240 blocks
        gemm_mfma_avg_sk<<<dim3(6, 10, 4), 256, 0, stream>>>(
            yfb, ybb, DI_, opw, DI_,
            outP, (size_t)M_ * D_, D_, M_, D_, 12, 4);
        reduce_sk2<<<dim3((M_ * D_ + 255) / 256, 1), 256, 0, stream>>>(
            outP, (size_t)M_ * D_, 4, nullptr,
            x, nullptr, nullptr, nullptr, M_ * D_, D_, 0);
    }

    // --- head ---
    final_rms<<<B_, 256, 0, stream>>>(res, x, norm_f_w, clsv);
    gemm_bt<<<dim3(16, 1), 256, 0, stream>>>(clsv, D_, head_w, D_, head_b,
                                             (float*)d_out, 1000, B_, 1000, D_, 1);
}

// Round 3
// 5967.567 us; speedup vs baseline: 1.8118x; 1.0871x over previous
//
#include <hip/hip_runtime.h>
#include <hip/hip_bf16.h>
#include <math.h>

#define B_ 4
#define L_ 301
#define D_ 768
#define DI_ 1536
#define NP_ 300
#define POS_ 150
#define M_ 1204
#define NC_ 5
#define CL_ 64

typedef __bf16 bf16;
typedef __attribute__((ext_vector_type(8))) __bf16 bf16x8;
typedef __attribute__((ext_vector_type(4))) float floatx4;

__device__ __forceinline__ float siluf(float x) { return x / (1.f + __expf(-x)); }
__device__ __forceinline__ float softplusf(float x) { return x > 20.f ? x : log1pf(__expf(x)); }

// ---------------------------------------------------------------------------
// MFMA bf16 GEMM, z-batched, 2-phase prefetch (double-buffered LDS):
// stage(k+1) issued BEFORE compute(k); one barrier per K-step.
// C[M,Nw] = act(A[M,K]bf16 @ W[Nw,K]f32^T + bias)
// ---------------------------------------------------------------------------
__global__ __launch_bounds__(256) void gemm_mfma(
    const bf16* __restrict__ A0, const bf16* __restrict__ A1, int lda,
    const float* __restrict__ W0, const float* __restrict__ W1, int ldw,
    const float* __restrict__ bias0, const float* __restrict__ bias1,
    float* __restrict__ C0, float* __restrict__ C1,
    bf16* __restrict__ Cb0, bf16* __restrict__ Cb1, int ldc,
    int M, int Nw, int Kw, int Ksteps, int act)
{
    const int zz = blockIdx.z;
    const bf16* A = zz ? A1 : A0;
    const float* W = zz ? W1 : W0;
    const float* bias = zz ? bias1 : bias0;
    float* C = zz ? C1 : C0;
    bf16* Cb = zz ? Cb1 : Cb0;

    __shared__ bf16 As[2][128 * 32];
    __shared__ bf16 Ws[2][128 * 32];
    const int t = threadIdx.x;
    const int bm = blockIdx.y * 128;
    const int bn = blockIdx.x * 128;
    const int lane = t & 63;
    const int wid = t >> 6;
    const int wr = wid >> 1, wc = wid & 1;
    const int ar = t >> 2;
    const int ac = (t & 3) * 8;
    const bool fullNK = ((Nw & 127) == 0) && ((Kw & 31) == 0);

    int gmr[2], gnr[2];
#pragma unroll
    for (int c2 = 0; c2 < 2; c2++) {
        int gm = bm + ar + c2 * 64; if (gm >= M) gm = M - 1;
        gmr[c2] = gm;
        gnr[c2] = bn + ar + c2 * 64;
    }

    floatx4 acc[4][4] = {};
    float vv[2][8];

    // ---- prologue: stage k=0 into buf 0 ----
#pragma unroll
    for (int c2 = 0; c2 < 2; c2++) {
        const bf16* gp = A + (size_t)gmr[c2] * lda + ac;
        __builtin_amdgcn_global_load_lds(
            (const __attribute__((address_space(1))) void*)gp,
            (__attribute__((address_space(3))) void*)(&As[0][0] + (ar + c2 * 64) * 32 + ac),
            16, 0, 0);
    }
#pragma unroll
    for (int c2 = 0; c2 < 2; c2++) {
        if (fullNK) {
            const floatx4* wp4 = (const floatx4*)(W + (size_t)gnr[c2] * ldw + ac);
            floatx4 a4 = wp4[0], b4 = wp4[1];
#pragma unroll
            for (int e = 0; e < 4; e++) { vv[c2][e] = a4[e]; vv[c2][e + 4] = b4[e]; }
        } else {
            const float* wp = W + (size_t)gnr[c2] * ldw + ac;
#pragma unroll
            for (int e = 0; e < 8; e++) {
                int kk = ac + e;
                vv[c2][e] = (gnr[c2] < Nw && kk < Kw) ? wp[e] : 0.f;
            }
        }
    }
#pragma unroll
    for (int c2 = 0; c2 < 2; c2++) {
        bf16x8 pk;
#pragma unroll
        for (int e = 0; e < 8; e++) pk[e] = (bf16)vv[c2][e];
        *(bf16x8*)(&Ws[0][0] + (ar + c2 * 64) * 32 + ac) = pk;
    }
    __syncthreads();

    for (int ks = 0; ks < Ksteps; ks++) {
        const int cur = ks & 1, nxt = cur ^ 1;
        const bool pf = (ks + 1 < Ksteps);
        if (pf) {
            const int k0 = (ks + 1) * 32;
#pragma unroll
            for (int c2 = 0; c2 < 2; c2++) {
                const bf16* gp = A + (size_t)gmr[c2] * lda + k0 + ac;
                __builtin_amdgcn_global_load_lds(
                    (const __attribute__((address_space(1))) void*)gp,
                    (__attribute__((address_space(3))) void*)(&As[nxt][0] + (ar + c2 * 64) * 32 + ac),
                    16, 0, 0);
            }
#pragma unroll
            for (int c2 = 0; c2 < 2; c2++) {
                if (fullNK) {
                    const floatx4* wp4 = (const floatx4*)(W + (size_t)gnr[c2] * ldw + k0 + ac);
                    floatx4 a4 = wp4[0], b4 = wp4[1];
#pragma unroll
                    for (int e = 0; e < 4; e++) { vv[c2][e] = a4[e]; vv[c2][e + 4] = b4[e]; }
                } else {
                    const float* wp = W + (size_t)gnr[c2] * ldw + k0 + ac;
#pragma unroll
                    for (int e = 0; e < 8; e++) {
                        int kk = k0 + ac + e;
                        vv[c2][e] = (gnr[c2] < Nw && kk < Kw) ? wp[e] : 0.f;
                    }
                }
            }
        }
        const int ra = wr * 64 + (lane & 15);
        const int rb = wc * 64 + (lane & 15);
        const int kb = (lane >> 4) * 8;
        bf16x8 af[4], bfm[4];
#pragma unroll
        for (int i = 0; i < 4; i++)
            af[i] = *(const bf16x8*)(&As[cur][0] + (ra + i * 16) * 32 + kb);
#pragma unroll
        for (int j = 0; j < 4; j++)
            bfm[j] = *(const bf16x8*)(&Ws[cur][0] + (rb + j * 16) * 32 + kb);
#pragma unroll
        for (int i = 0; i < 4; i++)
#pragma unroll
            for (int j = 0; j < 4; j++)
                acc[i][j] = __builtin_amdgcn_mfma_f32_16x16x32_bf16(af[i], bfm[j], acc[i][j], 0, 0, 0);
        if (pf) {
#pragma unroll
            for (int c2 = 0; c2 < 2; c2++) {
                bf16x8 pk;
#pragma unroll
                for (int e = 0; e < 8; e++) pk[e] = (bf16)vv[c2][e];
                *(bf16x8*)(&Ws[nxt][0] + (ar + c2 * 64) * 32 + ac) = pk;
            }
        }
        __syncthreads();
    }
#pragma unroll
    for (int i = 0; i < 4; i++) {
#pragma unroll
        for (int j = 0; j < 4; j++) {
            int n = bn + wc * 64 + j * 16 + (lane & 15);
            if (n >= Nw) continue;
            float bv = (act >= 1) ? bias[n] : 0.f;
#pragma unroll
            for (int r = 0; r < 4; r++) {
                int m = bm + wr * 64 + i * 16 + (lane >> 4) * 4 + r;
                if (m >= M) continue;
                float v = acc[i][j][r] + bv;
                if (act == 2) v = softplusf(v);
                C[(size_t)m * ldc + n] = v;
                if (Cb) Cb[(size_t)m * ldc + n] = (bf16)v;
            }
        }
    }
}

// ---------------------------------------------------------------------------
// Split-K MFMA GEMM (2-dir), 2-phase prefetch. blockIdx.z = dir*SK + chunk.
// ---------------------------------------------------------------------------
__global__ __launch_bounds__(256) void gemm_mfma_sk(
    const bf16* __restrict__ A0, const bf16* __restrict__ A1, int lda,
    const float* __restrict__ W0, const float* __restrict__ W1, int ldw,
    float* __restrict__ Cp, size_t chunkStride, int ldc,
    int M, int Nw, int KstepsPer, int SK)
{
    const int z = blockIdx.z;
    const int dir = z / SK;
    const int chunk = z % SK;
    const bf16* A = dir ? A1 : A0;
    const float* W = dir ? W1 : W0;
    float* C = Cp + (size_t)z * chunkStride;
    const int kbase = chunk * KstepsPer * 32;

    __shared__ bf16 As[2][128 * 32];
    __shared__ bf16 Ws[2][128 * 32];
    const int t = threadIdx.x;
    const int bm = blockIdx.y * 128;
    const int bn = blockIdx.x * 128;
    const int lane = t & 63;
    const int wid = t >> 6;
    const int wr = wid >> 1, wc = wid & 1;
    const int ar = t >> 2;
    const int ac = (t & 3) * 8;

    int gmr[2], gnr[2];
#pragma unroll
    for (int c2 = 0; c2 < 2; c2++) {
        int gm = bm + ar + c2 * 64; if (gm >= M) gm = M - 1;
        gmr[c2] = gm;
        gnr[c2] = bn + ar + c2 * 64;
    }

    floatx4 acc[4][4] = {};
    float vv[2][8];

    // prologue
#pragma unroll
    for (int c2 = 0; c2 < 2; c2++) {
        const bf16* gp = A + (size_t)gmr[c2] * lda + kbase + ac;
        __builtin_amdgcn_global_load_lds(
            (const __attribute__((address_space(1))) void*)gp,
            (__attribute__((address_space(3))) void*)(&As[0][0] + (ar + c2 * 64) * 32 + ac),
            16, 0, 0);
    }
#pragma unroll
    for (int c2 = 0; c2 < 2; c2++) {
        if (gnr[c2] < Nw) {
            const floatx4* wp4 = (const floatx4*)(W + (size_t)gnr[c2] * ldw + kbase + ac);
            floatx4 a4 = wp4[0], b4 = wp4[1];
#pragma unroll
            for (int e = 0; e < 4; e++) { vv[c2][e] = a4[e]; vv[c2][e + 4] = b4[e]; }
        } else {
#pragma unroll
            for (int e = 0; e < 8; e++) vv[c2][e] = 0.f;
        }
    }
#pragma unroll
    for (int c2 = 0; c2 < 2; c2++) {
        bf16x8 pk;
#pragma unroll
        for (int e = 0; e < 8; e++) pk[e] = (bf16)vv[c2][e];
        *(bf16x8*)(&Ws[0][0] + (ar + c2 * 64) * 32 + ac) = pk;
    }
    __syncthreads();

    for (int ks = 0; ks < KstepsPer; ks++) {
        const int cur = ks & 1, nxt = cur ^ 1;
        const bool pf = (ks + 1 < KstepsPer);
        if (pf) {
            const int k0 = kbase + (ks + 1) * 32;
#pragma unroll
            for (int c2 = 0; c2 < 2; c2++) {
                const bf16* gp = A + (size_t)gmr[c2] * lda + k0 + ac;
                __builtin_amdgcn_global_load_lds(
                    (const __attribute__((address_space(1))) void*)gp,
                    (__attribute__((address_space(3))) void*)(&As[nxt][0] + (ar + c2 * 64) * 32 + ac),
                    16, 0, 0);
            }
#pragma unroll
            for (int c2 = 0; c2 < 2; c2++) {
                if (gnr[c2] < Nw) {
                    const floatx4* wp4 = (const floatx4*)(W + (size_t)gnr[c2] * ldw + k0 + ac);
                    floatx4 a4 = wp4[0], b4 = wp4[1];
#pragma unroll
                    for (int e = 0; e < 4; e++) { vv[c2][e] = a4[e]; vv[c2][e + 4] = b4[e]; }
                } else {
#pragma unroll
                    for (int e = 0; e < 8; e++) vv[c2][e] = 0.f;
                }
            }
        }
        const int ra = wr * 64 + (lane & 15);
        const int rb = wc * 64 + (lane & 15);
        const int kb = (lane >> 4) * 8;
        bf16x8 af[4], bfm[4];
#pragma unroll
        for (int i = 0; i < 4; i++)
            af[i] = *(const bf16x8*)(&As[cur][0] + (ra + i * 16) * 32 + kb);
#pragma unroll
        for (int j = 0; j < 4; j++)
            bfm[j] = *(const bf16x8*)(&Ws[cur][0] + (rb + j * 16) * 32 + kb);
#pragma unroll
        for (int i = 0; i < 4; i++)
#pragma unroll
            for (int j = 0; j < 4; j++)
                acc[i][j] = __builtin_amdgcn_mfma_f32_16x16x32_bf16(af[i], bfm[j], acc[i][j], 0, 0, 0);
        if (pf) {
#pragma unroll
            for (int c2 = 0; c2 < 2; c2++) {
                bf16x8 pk;
#pragma unroll
                for (int e = 0; e < 8; e++) pk[e] = (bf16)vv[c2][e];
                *(bf16x8*)(&Ws[nxt][0] + (ar + c2 * 64) * 32 + ac) = pk;
            }
        }
        __syncthreads();
    }
#pragma unroll
    for (int i = 0; i < 4; i++) {
#pragma unroll
        for (int j = 0; j < 4; j++) {
            int n = bn + wc * 64 + j * 16 + (lane & 15);
            if (n >= Nw) continue;
#pragma unroll
            for (int r = 0; r < 4; r++) {
                int m = bm + wr * 64 + i * 16 + (lane >> 4) * 4 + r;
                if (m >= M) continue;
                C[(size_t)m * ldc + n] = acc[i][j][r];
            }
        }
    }
}

// ---------------------------------------------------------------------------
// out_proj split-K GEMM, 2-phase prefetch. A = bf16(0.5*(Af+Ab)) reg-staged.
// ---------------------------------------------------------------------------
__global__ __launch_bounds__(256) void gemm_mfma_avg_sk(
    const bf16* __restrict__ Af, const bf16* __restrict__ Ab, int lda,
    const float* __restrict__ W, int ldw,
    float* __restrict__ Cp, size_t chunkStride, int ldc,
    int M, int Nw, int KstepsPer, int SK)
{
    const int chunk = blockIdx.z;
    float* C = Cp + (size_t)chunk * chunkStride;
    const int kbase = chunk * KstepsPer * 32;

    __shared__ bf16 As[2][128 * 32];
    __shared__ bf16 Ws[2][128 * 32];
    const int t = threadIdx.x;
    const int bm = blockIdx.y * 128;
    const int bn = blockIdx.x * 128;
    const int lane = t & 63;
    const int wid = t >> 6;
    const int wr = wid >> 1, wc = wid & 1;
    const int ar = t >> 2;
    const int ac = (t & 3) * 8;

    int gmr[2], gnr[2];
#pragma unroll
    for (int c2 = 0; c2 < 2; c2++) {
        int gm = bm + ar + c2 * 64; if (gm >= M) gm = M - 1;
        gmr[c2] = gm;
        gnr[c2] = bn + ar + c2 * 64;
    }

    floatx4 acc[4][4] = {};
    bf16x8 a8[2], b8[2];
    float vv[2][8];

    // prologue
#pragma unroll
    for (int c2 = 0; c2 < 2; c2++) {
        a8[c2] = *(const bf16x8*)(Af + (size_t)gmr[c2] * lda + kbase + ac);
        b8[c2] = *(const bf16x8*)(Ab + (size_t)gmr[c2] * lda + kbase + ac);
        const floatx4* wp4 = (const floatx4*)(W + (size_t)gnr[c2] * ldw + kbase + ac);
        floatx4 w4 = wp4[0], x4 = wp4[1];
#pragma unroll
        for (int e = 0; e < 4; e++) { vv[c2][e] = w4[e]; vv[c2][e + 4] = x4[e]; }
    }
#pragma unroll
    for (int c2 = 0; c2 < 2; c2++) {
        bf16x8 pa, pw;
#pragma unroll
        for (int e = 0; e < 8; e++) {
            pa[e] = (bf16)(0.5f * ((float)a8[c2][e] + (float)b8[c2][e]));
            pw[e] = (bf16)vv[c2][e];
        }
        *(bf16x8*)(&As[0][0] + (ar + c2 * 64) * 32 + ac) = pa;
        *(bf16x8*)(&Ws[0][0] + (ar + c2 * 64) * 32 + ac) = pw;
    }
    __syncthreads();

    for (int ks = 0; ks < KstepsPer; ks++) {
        const int cur = ks & 1, nxt = cur ^ 1;
        const bool pf = (ks + 1 < KstepsPer);
        if (pf) {
            const int k0 = kbase + (ks + 1) * 32;
#pragma unroll
            for (int c2 = 0; c2 < 2; c2++) {
                a8[c2] = *(const bf16x8*)(Af + (size_t)gmr[c2] * lda + k0 + ac);
                b8[c2] = *(const bf16x8*)(Ab + (size_t)gmr[c2] * lda + k0 + ac);
                const floatx4* wp4 = (const floatx4*)(W + (size_t)gnr[c2] * ldw + k0 + ac);
                floatx4 w4 = wp4[0], x4 = wp4[1];
#pragma unroll
                for (int e = 0; e < 4; e++) { vv[c2][e] = w4[e]; vv[c2][e + 4] = x4[e]; }
            }
        }
        const int ra = wr * 64 + (lane & 15);
        const int rb = wc * 64 + (lane & 15);
        const int kb = (lane >> 4) * 8;
        bf16x8 af[4], bfm[4];
#pragma unroll
        for (int i = 0; i < 4; i++)
            af[i] = *(const bf16x8*)(&As[cur][0] + (ra + i * 16) * 32 + kb);
#pragma unroll
        for (int j = 0; j < 4; j++)
            bfm[j] = *(const bf16x8*)(&Ws[cur][0] + (rb + j * 16) * 32 + kb);
#pragma unroll
        for (int i = 0; i < 4; i++)
#pragma unroll
            for (int j = 0; j < 4; j++)
                acc[i][j] = __builtin_amdgcn_mfma_f32_16x16x32_bf16(af[i], bfm[j], acc[i][j], 0, 0, 0);
        if (pf) {
#pragma unroll
            for (int c2 = 0; c2 < 2; c2++) {
                bf16x8 pa, pw;
#pragma unroll
                for (int e = 0; e < 8; e++) {
                    pa[e] = (bf16)(0.5f * ((float)a8[c2][e] + (float)b8[c2][e]));
                    pw[e] = (bf16)vv[c2][e];
                }
                *(bf16x8*)(&As[nxt][0] + (ar + c2 * 64) * 32 + ac) = pa;
                *(bf16x8*)(&Ws[nxt][0] + (ar + c2 * 64) * 32 + ac) = pw;
            }
        }
        __syncthreads();
    }
#pragma unroll
    for (int i = 0; i < 4; i++) {
#pragma unroll
        for (int j = 0; j < 4; j++) {
            int n = bn + wc * 64 + j * 16 + (lane & 15);
            if (n >= Nw) continue;
#pragma unroll
            for (int r = 0; r < 4; r++) {
                int m = bm + wr * 64 + i * 16 + (lane >> 4) * 4 + r;
                if (m >= M) continue;
                C[(size_t)m * ldc + n] = acc[i][j][r];
            }
        }
    }
}

// ---------------------------------------------------------------------------
// Split-K reduce: C = act(sum_chunks Cp + bias); optional bf16 mirror.
// ---------------------------------------------------------------------------
__global__ void reduce_sk2(const float* __restrict__ Cp, size_t chunkStride, int SK,
                           const float* __restrict__ bias0,
                           float* __restrict__ C0, float* __restrict__ C1,
                           bf16* __restrict__ Cb0, bf16* __restrict__ Cb1,
                           int total, int ldn, int act)
{
    const int dir = blockIdx.y;
    const float* P = Cp + (size_t)dir * SK * chunkStride;
    float* C = dir ? C1 : C0;
    bf16* Cb = dir ? Cb1 : Cb0;
    int idx = blockIdx.x * 256 + threadIdx.x;
    if (idx >= total) return;
    float s = 0.f;
    for (int c = 0; c < SK; c++) s += P[(size_t)c * chunkStride + idx];
    if (act >= 1) s += bias0[idx % ldn];
    if (act == 2) s = softplusf(s);
    C[idx] = s;
    if (Cb) Cb[idx] = (bf16)s;
}

// ---------------------------------------------------------------------------
// Patch-embed MFMA GEMM, split-K (SK=8) + 2-phase prefetch (both reg-staged).
// ---------------------------------------------------------------------------
__global__ __launch_bounds__(256) void gemm_patch_mfma(
    const float* __restrict__ img, const float* __restrict__ W,
    float* __restrict__ Cp)
{
    __shared__ bf16 As[2][128 * 32];
    __shared__ bf16 Ws[2][128 * 32];
    const int t = threadIdx.x;
    const int bm = blockIdx.y * 128;
    const int bn = blockIdx.x * 128;
    const int chunk = blockIdx.z;
    const int lane = t & 63;
    const int wid = t >> 6;
    const int wr = wid >> 1, wc = wid & 1;
    const int ar = t >> 2;
    const int ac = (t & 3) * 8;
    const int M = 1200, ldw = 12288, ldc = 768;
    const int kbase = chunk * 1536;
    float* C = Cp + (size_t)chunk * M * ldc;

    const float* abase[2];
    int gnr[2];
#pragma unroll
    for (int c2 = 0; c2 < 2; c2++) {
        int gm = bm + ar + c2 * 64; if (gm >= M) gm = M - 1;
        int b = gm / 300, rem = gm % 300;
        int gi = rem / 15, gj = rem % 15;
        abase[c2] = img + ((size_t)(b * 3) * 1280 + gi * 64) * 960 + gj * 64;
        gnr[c2] = bn + ar + c2 * 64;
    }

    floatx4 acc[4][4] = {};
    float av[2][8], vv[2][8];

    // prologue: k = kbase + ac
    {
        const int k = kbase + ac;
        const int q = k & 63, p = (k >> 6) & 63, c = k >> 12;
#pragma unroll
        for (int c2 = 0; c2 < 2; c2++) {
            const floatx4* ip4 = (const floatx4*)(abase[c2] + ((size_t)c * 1280 + p) * 960 + q);
            floatx4 i4 = ip4[0], j4 = ip4[1];
            const floatx4* wp4 = (const floatx4*)(W + (size_t)gnr[c2] * ldw + k);
            floatx4 w4 = wp4[0], x4 = wp4[1];
#pragma unroll
            for (int e = 0; e < 4; e++) {
                av[c2][e] = i4[e]; av[c2][e + 4] = j4[e];
                vv[c2][e] = w4[e]; vv[c2][e + 4] = x4[e];
            }
        }
#pragma unroll
        for (int c2 = 0; c2 < 2; c2++) {
            bf16x8 pa, pw;
#pragma unroll
            for (int e = 0; e < 8; e++) { pa[e] = (bf16)av[c2][e]; pw[e] = (bf16)vv[c2][e]; }
            *(bf16x8*)(&As[0][0] + (ar + c2 * 64) * 32 + ac) = pa;
            *(bf16x8*)(&Ws[0][0] + (ar + c2 * 64) * 32 + ac) = pw;
        }
    }
    __syncthreads();

    for (int ks = 0; ks < 48; ks++) {
        const int cur = ks & 1, nxt = cur ^ 1;
        const bool pf = (ks + 1 < 48);
        if (pf) {
            const int k = kbase + (ks + 1) * 32 + ac;
            const int q = k & 63, p = (k >> 6) & 63, c = k >> 12;
#pragma unroll
            for (int c2 = 0; c2 < 2; c2++) {
                const floatx4* ip4 = (const floatx4*)(abase[c2] + ((size_t)c * 1280 + p) * 960 + q);
                floatx4 i4 = ip4[0], j4 = ip4[1];
                const floatx4* wp4 = (const floatx4*)(W + (size_t)gnr[c2] * ldw + k);
                floatx4 w4 = wp4[0], x4 = wp4[1];
#pragma unroll
                for (int e = 0; e < 4; e++) {
                    av[c2][e] = i4[e]; av[c2][e + 4] = j4[e];
                    vv[c2][e] = w4[e]; vv[c2][e + 4] = x4[e];
                }
            }
        }
        const int ra = wr * 64 + (lane & 15);
        const int rb = wc * 64 + (lane & 15);
        const int kb = (lane >> 4) * 8;
        bf16x8 af[4], bfm[4];
#pragma unroll
        for (int i = 0; i < 4; i++)
            af[i] = *(const bf16x8*)(&As[cur][0] + (ra + i * 16) * 32 + kb);
#pragma unroll
        for (int j = 0; j < 4; j++)
            bfm[j] = *(const bf16x8*)(&Ws[cur][0] + (rb + j * 16) * 32 + kb);
#pragma unroll
        for (int i = 0; i < 4; i++)
#pragma unroll
            for (int j = 0; j < 4; j++)
                acc[i][j] = __builtin_amdgcn_mfma_f32_16x16x32_bf16(af[i], bfm[j], acc[i][j], 0, 0, 0);
        if (pf) {
#pragma unroll
            for (int c2 = 0; c2 < 2; c2++) {
                bf16x8 pa, pw;
#pragma unroll
                for (int e = 0; e < 8; e++) { pa[e] = (bf16)av[c2][e]; pw[e] = (bf16)vv[c2][e]; }
                *(bf16x8*)(&As[nxt][0] + (ar + c2 * 64) * 32 + ac) = pa;
                *(bf16x8*)(&Ws[nxt][0] + (ar + c2 * 64) * 32 + ac) = pw;
            }
        }
        __syncthreads();
    }
#pragma unroll
    for (int i = 0; i < 4; i++) {
#pragma unroll
        for (int j = 0; j < 4; j++) {
            int n = bn + wc * 64 + j * 16 + (lane & 15);
#pragma unroll
            for (int r = 0; r < 4; r++) {
                int m = bm + wr * 64 + i * 16 + (lane >> 4) * 4 + r;
                if (m >= M) continue;
                C[(size_t)m * ldc + n] = acc[i][j][r];
            }
        }
    }
}

// ---------------------------------------------------------------------------
// fp32 GEMM for the tiny head matmul.
// ---------------------------------------------------------------------------
__global__ void gemm_bt(const float* __restrict__ A, int lda,
                        const float* __restrict__ W, int ldw,
                        const float* __restrict__ bias,
                        float* __restrict__ C, int ldc,
                        int M, int N, int K, int act) {
    __shared__ float As[16][68];
    __shared__ float Ws[16][68];
    const int tid = threadIdx.x;
    const int bm = blockIdx.y * 64;
    const int bn = blockIdx.x * 64;
    const int tx = tid & 15, ty = tid >> 4;
    float acc[4][4] = {};
    const int lk = tid & 15;
    const int lm = tid >> 4;
    for (int k0 = 0; k0 < K; k0 += 16) {
        const int ak = k0 + lk;
#pragma unroll
        for (int i = 0; i < 4; i++) {
            int m = bm + lm + i * 16;
            float v = 0.f;
            if (m < M && ak < K) v = A[(long)m * lda + ak];
            As[lk][lm + i * 16] = v;
        }
#pragma unroll
        for (int i = 0; i < 4; i++) {
            int n = bn + lm + i * 16;
            float v = 0.f;
            if (n < N && ak < K) v = W[(long)n * ldw + ak];
            Ws[lk][lm + i * 16] = v;
        }
        __syncthreads();
#pragma unroll
        for (int kk = 0; kk < 16; kk++) {
            float a[4], w[4];
#pragma unroll
            for (int i = 0; i < 4; i++) a[i] = As[kk][ty * 4 + i];
#pragma unroll
            for (int j = 0; j < 4; j++) w[j] = Ws[kk][tx * 4 + j];
#pragma unroll
            for (int i = 0; i < 4; i++)
#pragma unroll
                for (int j = 0; j < 4; j++) acc[i][j] += a[i] * w[j];
        }
        __syncthreads();
    }
#pragma unroll
    for (int i = 0; i < 4; i++) {
        int m = bm + ty * 4 + i;
        if (m >= M) continue;
#pragma unroll
        for (int j = 0; j < 4; j++) {
            int n = bn + tx * 4 + j;
            if (n >= N) continue;
            float v = acc[i][j];
            if (act >= 1) v += bias[n];
            C[(long)m * ldc + n] = v;
        }
    }
}

// ---------------------------------------------------------------------------
__global__ void assemble(const float* __restrict__ xt, const float* __restrict__ cls,
                         const float* __restrict__ pos, float* __restrict__ x,
                         float* __restrict__ res) {
    int idx = blockIdx.x * 256 + threadIdx.x;
    if (idx >= B_ * L_ * D_) return;
    int d = idx % D_;
    int l = (idx / D_) % L_;
    int b = idx / (D_ * L_);
    float v;
    if (l == POS_) {
        v = cls[d];
    } else {
        int p = (l < POS_) ? l : l - 1;
        v = xt[((long)b * NP_ + p) * D_ + d];
    }
    x[idx] = v + pos[l * D_ + d];
    res[idx] = 0.f;
}

// res += h ; hn = bf16(rms(res) * w)
__global__ void add_rms(float* __restrict__ res, const float* __restrict__ h,
                        const float* __restrict__ w, bf16* __restrict__ hn) {
    int row = blockIdx.x;
    float* rr = res + (long)row * D_;
    const float* hr = h + (long)row * D_;
    float v[3];
    float ss = 0.f;
#pragma unroll
    for (int i = 0; i < 3; i++) {
        int d = threadIdx.x + i * 256;
        float t = rr[d] + hr[d];
        v[i] = t;
        ss += t * t;
    }
#pragma unroll
    for (int off = 1; off < 64; off <<= 1) ss += __shfl_xor(ss, off);
    __shared__ float red[4];
    __shared__ float inv;
    if ((threadIdx.x & 63) == 0) red[threadIdx.x >> 6] = ss;
    __syncthreads();
    if (threadIdx.x == 0) {
        float s = red[0] + red[1] + red[2] + red[3];
        inv = rsqrtf(s / (float)D_ + 1e-5f);
    }
    __syncthreads();
    float iv = inv;
#pragma unroll
    for (int i = 0; i < 3; i++) {
        int d = threadIdx.x + i * 256;
        rr[d] = v[i];
        hn[(long)row * D_ + d] = (bf16)(v[i] * iv * w[d]);
    }
}

// Depthwise causal conv (K=4) + silu, both directions in one dispatch.
__global__ void conv_silu2(const float* __restrict__ xz,
                           const float* __restrict__ wf, const float* __restrict__ bf_,
                           const float* __restrict__ wb, const float* __restrict__ bb_,
                           float* __restrict__ of, bf16* __restrict__ ofb,
                           float* __restrict__ ob, bf16* __restrict__ obb) {
    int idx = blockIdx.x * 256 + threadIdx.x;
    if (idx >= B_ * L_ * DI_) return;
    const int rev = blockIdx.y;
    const float* w = rev ? wb : wf;
    const float* bias = rev ? bb_ : bf_;
    float* out = rev ? ob : of;
    bf16* outb = rev ? obb : ofb;
    int d = idx % DI_;
    int l = (idx / DI_) % L_;
    int b = idx / (DI_ * L_);
    float acc = bias[d];
#pragma unroll
    for (int k = 0; k < 4; k++) {
        int ls = l - 3 + k;
        if (ls < 0) continue;
        int lsrc = rev ? (L_ - 1 - ls) : ls;
        acc += xz[((long)(b * L_ + lsrc)) * (2 * DI_) + d] * w[d * 4 + k];
    }
    float v = siluf(acc);
    out[idx] = v;
    outb[idx] = (bf16)v;
}

// ---------------------------------------------------------------------------
// Register-state chunked two-pass SSM scan.
// Thread owns (b,d): h[0..15] in VGPRs. No cross-lane ops, no barriers in the
// step loop. Bm/Cm broadcast from LDS; dt/xc/z coalesced global loads; y
// written directly as bf16 (coalesced). Carry = h[16] + sum(dt) scalar
// (chunk transition = exp(a*sum_dt) since a is time-constant).
// ---------------------------------------------------------------------------
__global__ __launch_bounds__(256) void ssm_p1(
    const float* __restrict__ xcF, const float* __restrict__ dtF, const float* __restrict__ dblF,
    const float* __restrict__ xcB, const float* __restrict__ dtB, const float* __restrict__ dblB,
    const float* __restrict__ AF, const float* __restrict__ AB,
    float* __restrict__ Hend, float* __restrict__ Sdt)
{
    const int rev = blockIdx.y;
    const int c = blockIdx.z;                // 0..NC_-2
    const float* xc = rev ? xcB : xcF;
    const float* dt = rev ? dtB : dtF;
    const float* dbl = rev ? dblB : dblF;
    const float* Alog = rev ? AB : AF;

    const int t = threadIdx.x;
    const int gb = blockIdx.x;               // 0..23 = b(4) x dgrp(6)
    const int b = gb / (DI_ / 256);
    const int d = (gb % (DI_ / 256)) * 256 + t;

    __shared__ float bm_s[CL_][16];
    const size_t rowbase = (size_t)b * L_;
    const int c0 = c * CL_;

    for (int i = t; i < CL_ * 16; i += 256) {
        int ll = i >> 4, n = i & 15;
        bm_s[ll][n] = dbl[(rowbase + c0 + ll) * 80 + 48 + n];
    }

    float a[16];
    const floatx4* ap = (const floatx4*)(Alog + (size_t)d * 16);
#pragma unroll
    for (int q = 0; q < 4; q++) {
        floatx4 v = ap[q];
#pragma unroll
        for (int e = 0; e < 4; e++) a[q * 4 + e] = -__expf(v[e]);
    }
    __syncthreads();

    float h[16];
#pragma unroll
    for (int n = 0; n < 16; n++) h[n] = 0.f;
    float sdt = 0.f;
    for (int ll = 0; ll < CL_; ll++) {
        size_t r = (rowbase + c0 + ll) * DI_ + d;
        float dtv = dt[r];
        float xcv = xc[r];
        float dbu = dtv * xcv;
        sdt += dtv;
#pragma unroll
        for (int n = 0; n < 16; n++)
            h[n] = __expf(dtv * a[n]) * h[n] + dbu * bm_s[ll][n];
    }
    size_t ob = (size_t)(rev * (NC_ - 1) + c) * B_ + b;
#pragma unroll
    for (int n = 0; n < 16; n++)
        Hend[(ob * 16 + n) * DI_ + d] = h[n];
    Sdt[ob * DI_ + d] = sdt;
}

__global__ __launch_bounds__(256) void ssm_p2(
    const float* __restrict__ xcF, const float* __restrict__ dtF, const float* __restrict__ dblF,
    const float* __restrict__ xcB, const float* __restrict__ dtB, const float* __restrict__ dblB,
    const float* __restrict__ xz,
    const float* __restrict__ AF, const float* __restrict__ DF,
    const float* __restrict__ AB, const float* __restrict__ DB,
    const float* __restrict__ Hend, const float* __restrict__ Sdt,
    bf16* __restrict__ yF, bf16* __restrict__ yB)
{
    const int rev = blockIdx.y;
    const int c = blockIdx.z;                // 0..NC_-1
    const float* xc = rev ? xcB : xcF;
    const float* dt = rev ? dtB : dtF;
    const float* dbl = rev ? dblB : dblF;
    const float* Alog = rev ? AB : AF;
    const float* Dp = rev ? DB : DF;
    bf16* yout = rev ? yB : yF;

    const int t = threadIdx.x;
    const int gb = blockIdx.x;
    const int b = gb / (DI_ / 256);
    const int d = (gb % (DI_ / 256)) * 256 + t;

    __shared__ float bm_s[CL_][16];
    __shared__ float cm_s[CL_][16];
    const size_t rowbase = (size_t)b * L_;
    const int c0 = c * CL_;
    const int Tc = min(CL_, L_ - c0);

    for (int i = t; i < Tc * 16; i += 256) {
        int ll = i >> 4, n = i & 15;
        size_t rb8 = (rowbase + c0 + ll) * 80;
        bm_s[ll][n] = dbl[rb8 + 48 + n];
        cm_s[ll][n] = dbl[rb8 + 64 + n];
    }

    float a[16];
    const floatx4* ap = (const floatx4*)(Alog + (size_t)d * 16);
#pragma unroll
    for (int q = 0; q < 4; q++) {
        floatx4 v = ap[q];
#pragma unroll
        for (int e = 0; e < 4; e++) a[q * 4 + e] = -__expf(v[e]);
    }
    const float Dv = Dp[d];

    // carry combine across earlier chunks
    float h[16];
#pragma unroll
    for (int n = 0; n < 16; n++) h[n] = 0.f;
    for (int j = 0; j < c; j++) {
        size_t ob = (size_t)(rev * (NC_ - 1) + j) * B_ + b;
        float sd = Sdt[ob * DI_ + d];
#pragma unroll
        for (int n = 0; n < 16; n++)
            h[n] = __expf(a[n] * sd) * h[n] + Hend[(ob * 16 + n) * DI_ + d];
    }
    __syncthreads();

    for (int ll = 0; ll < Tc; ll++) {
        int l = c0 + ll;
        size_t r = (rowbase + l) * DI_ + d;
        float dtv = dt[r];
        float xcv = xc[r];
        int lo = rev ? (L_ - 1 - l) : l;
        float zv = xz[(rowbase + lo) * (2 * DI_) + DI_ + d];
        float dbu = dtv * xcv;
        float acc2 = 0.f;
#pragma unroll
        for (int n = 0; n < 16; n++) {
            h[n] = __expf(dtv * a[n]) * h[n] + dbu * bm_s[ll][n];
            acc2 += h[n] * cm_s[ll][n];
        }
        float yv = (acc2 + xcv * Dv) * siluf(zv);
        yout[(rowbase + lo) * DI_ + d] = (bf16)yv;
    }
}

__global__ void final_rms(const float* __restrict__ res, const float* __restrict__ h,
                          const float* __restrict__ w, float* __restrict__ out) {
    int b = blockIdx.x;
    long base = ((long)b * L_ + POS_) * D_;
    float v[3];
    float ss = 0.f;
#pragma unroll
    for (int i = 0; i < 3; i++) {
        int d = threadIdx.x + i * 256;
        float t = res[base + d] + h[base + d];
        v[i] = t;
        ss += t * t;
    }
#pragma unroll
    for (int off = 1; off < 64; off <<= 1) ss += __shfl_xor(ss, off);
    __shared__ float red[4];
    __shared__ float inv;
    if ((threadIdx.x & 63) == 0) red[threadIdx.x >> 6] = ss;
    __syncthreads();
    if (threadIdx.x == 0) {
        float s = red[0] + red[1] + red[2] + red[3];
        inv = rsqrtf(s / (float)D_ + 1e-5f);
    }
    __syncthreads();
    float iv = inv;
#pragma unroll
    for (int i = 0; i < 3; i++) {
        int d = threadIdx.x + i * 256;
        out[b * D_ + d] = v[i] * iv * w[d];
    }
}

// ---------------------------------------------------------------------------
extern "C" void kernel_launch(void* const* d_in, const int* in_sizes, int n_in,
                              void* d_out, int out_size, void* d_ws, size_t ws_size,
                              hipStream_t stream) {
    const float* img = (const float*)d_in[0];
    const float* patch_w = (const float*)d_in[1];
    const float* patch_b = (const float*)d_in[2];
    const float* cls_token = (const float*)d_in[3];
    const float* pos_embed = (const float*)d_in[4];
    const float* norm_w = (const float*)d_in[5];
    const float* in_proj_w = (const float*)d_in[6];
    const float* conv_f_w = (const float*)d_in[7];
    const float* conv_f_b = (const float*)d_in[8];
    const float* xproj_f_w = (const float*)d_in[9];
    const float* dt_f_w = (const float*)d_in[10];
    const float* dt_f_b = (const float*)d_in[11];
    const float* A_f_log = (const float*)d_in[12];
    const float* D_f = (const float*)d_in[13];
    const float* conv_b_w = (const float*)d_in[14];
    const float* conv_b_b = (const float*)d_in[15];
    const float* xproj_b_w = (const float*)d_in[16];
    const float* dt_b_w = (const float*)d_in[17];
    const float* dt_b_b = (const float*)d_in[18];
    const float* A_b_log = (const float*)d_in[19];
    const float* D_b = (const float*)d_in[20];
    const float* out_proj_w = (const float*)d_in[21];
    const float* norm_f_w = (const float*)d_in[22];
    const float* head_w = (const float*)d_in[23];
    const float* head_b = (const float*)d_in[24];

    char* p8 = (char*)d_ws;
    auto alloc = [&](size_t nb) { char* r = p8; p8 += (nb + 255) & ~(size_t)255; return r; };
    float* x    = (float*)alloc((size_t)M_ * D_ * 4);
    float* res  = (float*)alloc((size_t)M_ * D_ * 4);
    bf16*  hnb  = (bf16*) alloc((size_t)M_ * D_ * 2);
    float* xz   = (float*)alloc((size_t)M_ * 2 * DI_ * 4);
    float* xcf  = (float*)alloc((size_t)M_ * DI_ * 4);
    float* xcb  = (float*)alloc((size_t)M_ * DI_ * 4);
    bf16*  xcfb = (bf16*) alloc((size_t)M_ * DI_ * 2);
    bf16*  xcbb = (bf16*) alloc((size_t)M_ * DI_ * 2);
    float* dtf  = (float*)alloc((size_t)M_ * DI_ * 4);
    float* dtb  = (float*)alloc((size_t)M_ * DI_ * 4);
    bf16*  yfb  = (bf16*) alloc((size_t)M_ * DI_ * 2);
    bf16*  ybb  = (bf16*) alloc((size_t)M_ * DI_ * 2);
    float* dblf = (float*)alloc((size_t)M_ * 80 * 4);
    float* dblb = (float*)alloc((size_t)M_ * 80 * 4);
    bf16*  dblfb= (bf16*) alloc((size_t)M_ * 80 * 2);
    bf16*  dblbb= (bf16*) alloc((size_t)M_ * 80 * 2);
    float* clsv = (float*)alloc((size_t)B_ * D_ * 4);
    // reg-state scan carries: Hend [2][NC-1][B][16][DI], Sdt [2][NC-1][B][DI]
    float* hend = (float*)alloc((size_t)2 * (NC_ - 1) * B_ * 16 * DI_ * 4);
    float* sdtb = (float*)alloc((size_t)2 * (NC_ - 1) * B_ * DI_ * 4);
    float* xtmp = dtf;   // alias: xtmp consumed (assemble) before layer 0 writes dtf

    // Split-K partial buffers, aliased onto dead regions:
    float* patchP = xz;
    float* xprojP = dtf;
    float* outP   = dtf;

    // --- embed (split-K 8: 480 blocks) ---
    gemm_patch_mfma<<<dim3(6, 10, 8), 256, 0, stream>>>(img, patch_w, patchP);
    reduce_sk2<<<dim3((1200 * 768 + 255) / 256, 1), 256, 0, stream>>>(
        patchP, (size_t)1200 * 768, 8, patch_b, xtmp, nullptr, nullptr, nullptr,
        1200 * 768, 768, 1);
    assemble<<<(B_ * L_ * D_ + 255) / 256, 256, 0, stream>>>(xtmp, cls_token, pos_embed, x, res);

    // --- layers ---
    for (int layer = 0; layer < 24; layer++) {
        const float* ipw = in_proj_w + (size_t)layer * 2 * DI_ * D_;
        const float* cfw = conv_f_w + (size_t)layer * DI_ * 4;
        const float* cfb = conv_f_b + (size_t)layer * DI_;
        const float* xfw = xproj_f_w + (size_t)layer * 80 * DI_;
        const float* dfw = dt_f_w + (size_t)layer * DI_ * 48;
        const float* dfb = dt_f_b + (size_t)layer * DI_;
        const float* afl = A_f_log + (size_t)layer * DI_ * 16;
        const float* df = D_f + (size_t)layer * DI_;
        const float* cbw = conv_b_w + (size_t)layer * DI_ * 4;
        const float* cbb = conv_b_b + (size_t)layer * DI_;
        const float* xbw = xproj_b_w + (size_t)layer * 80 * DI_;
        const float* dbw = dt_b_w + (size_t)layer * DI_ * 48;
        const float* dbb = dt_b_b + (size_t)layer * DI_;
        const float* abl = A_b_log + (size_t)layer * DI_ * 16;
        const float* db = D_b + (size_t)layer * DI_;
        const float* opw = out_proj_w + (size_t)layer * D_ * DI_;
        const float* nw = norm_w + (size_t)layer * D_;

        add_rms<<<M_, 256, 0, stream>>>(res, x, nw, hnb);
        gemm_mfma<<<dim3(24, 10, 1), 256, 0, stream>>>(
            hnb, hnb, D_, ipw, ipw, D_, nullptr, nullptr,
            xz, xz, nullptr, nullptr, 2 * DI_, M_, 2 * DI_, D_, 24, 0);
        conv_silu2<<<dim3((B_ * L_ * DI_ + 255) / 256, 2), 256, 0, stream>>>(
            xz, cfw, cfb, cbw, cbb, xcf, xcfb, xcb, xcbb);
        // xproj split-K 8: 160 blocks
        gemm_mfma_sk<<<dim3(1, 10, 16), 256, 0, stream>>>(
            xcfb, xcbb, DI_, xfw, xbw, DI_,
            xprojP, (size_t)M_ * 80, 80, M_, 80, 6, 8);
        reduce_sk2<<<dim3((M_ * 80 + 255) / 256, 2), 256, 0, stream>>>(
            xprojP, (size_t)M_ * 80, 8, nullptr,
            dblf, dblb, dblfb, dblbb, M_ * 80, 80, 0);
        gemm_mfma<<<dim3(12, 10, 2), 256, 0, stream>>>(
            dblfb, dblbb, 80, dfw, dbw, 48, dfb, dbb,
            dtf, dtb, nullptr, nullptr, DI_, M_, DI_, 48, 2, 2);
        // register-state chunked two-pass scan
        ssm_p1<<<dim3(24, 2, NC_ - 1), 256, 0, stream>>>(
            xcf, dtf, dblf, xcb, dtb, dblb, afl, abl, hend, sdtb);
        ssm_p2<<<dim3(24, 2, NC_), 256, 0, stream>>>(
            xcf, dtf, dblf, xcb, dtb, dblb, xz, afl, df, abl, db,
            hend, sdtb, yfb, ybb);
        // out_proj split-K 4: 240 blocks
        gemm_mfma_avg_sk<<<dim3(6, 10, 4), 256, 0, stream>>>(
            yfb, ybb, DI_, opw, DI_,
            outP, (size_t)M_ * D_, D_, M_, D_, 12, 4);
        reduce_sk2<<<dim3((M_ * D_ + 255) / 256, 1), 256, 0, stream>>>(
            outP, (size_t)M_ * D_, 4, nullptr,
            x, nullptr, nullptr, nullptr, M_ * D_, D_, 0);
    }

    // --- head ---
    final_rms<<<B_, 256, 0, stream>>>(res, x, norm_f_w, clsv);
    gemm_bt<<<dim3(16, 1), 256, 0, stream>>>(clsv, D_, head_w, D_, head_b,
                                             (float*)d_out, 1000, B_, 1000, D_, 1);
}